// Round 7
// baseline (474.491 us; speedup 1.0000x reference)
//
#include <hip/hip_runtime.h>

// Problem constants (match reference setup_inputs)
#define NN 100000
#define NE 600000
#define NG 256
#define HID 128
#define BN_EPS 1e-5f

#define SCAN_TILE 1024
#define NTILES ((NN + SCAN_TILE - 1) / SCAN_TILE)  // 98
#define MM_TILES (NN / 32)                          // 3125 (NN % 32 == 0)

// ---------------- histogram of dst (in-degree) ----------------

__global__ __launch_bounds__(256) void hist_kernel(const int* __restrict__ dst, int* __restrict__ cnt) {
    int e = blockIdx.x * blockDim.x + threadIdx.x;
    if (e < NE) atomicAdd(&cnt[dst[e]], 1);
}

__global__ __launch_bounds__(256) void dinv_kernel(const int* __restrict__ cnt, float* __restrict__ dinv) {
    int n = blockIdx.x * blockDim.x + threadIdx.x;
    if (n < NN) dinv[n] = rsqrtf((float)cnt[n] + 1.0f);
}

// ---------------- 2-level exclusive scan of cnt -> row_start ----------------

__global__ __launch_bounds__(256) void scan_a(const int* __restrict__ cnt, int* __restrict__ rs,
                                              int* __restrict__ tsum) {
    __shared__ int s[256];
    int t = threadIdx.x;
    int base = blockIdx.x * SCAN_TILE;
    int idx = base + t * 4;
    int v0 = (idx + 0 < NN) ? cnt[idx + 0] : 0;
    int v1 = (idx + 1 < NN) ? cnt[idx + 1] : 0;
    int v2 = (idx + 2 < NN) ? cnt[idx + 2] : 0;
    int v3 = (idx + 3 < NN) ? cnt[idx + 3] : 0;
    int local = v0 + v1 + v2 + v3;
    s[t] = local;
    __syncthreads();
    for (int off = 1; off < 256; off <<= 1) {
        int x = (t >= off) ? s[t - off] : 0;
        __syncthreads();
        s[t] += x;
        __syncthreads();
    }
    int pre = s[t] - local;  // exclusive prefix within tile
    if (t == 255) tsum[blockIdx.x] = s[255];
    if (idx + 0 < NN) rs[idx + 0] = pre; pre += v0;
    if (idx + 1 < NN) rs[idx + 1] = pre; pre += v1;
    if (idx + 2 < NN) rs[idx + 2] = pre; pre += v2;
    if (idx + 3 < NN) rs[idx + 3] = pre;
}

__global__ __launch_bounds__(128) void scan_b(int* __restrict__ tsum) {
    __shared__ int s[128];
    int t = threadIdx.x;
    int v = (t < NTILES) ? tsum[t] : 0;
    s[t] = v;
    __syncthreads();
    for (int off = 1; off < 128; off <<= 1) {
        int x = (t >= off) ? s[t - off] : 0;
        __syncthreads();
        s[t] += x;
        __syncthreads();
    }
    if (t < NTILES) tsum[t] = s[t] - v;  // exclusive
}

__global__ __launch_bounds__(256) void scan_c(int* __restrict__ rs, const int* __restrict__ tsum,
                                              int* __restrict__ cursor) {
    int t = threadIdx.x;
    int base = blockIdx.x * SCAN_TILE;
    int off = tsum[blockIdx.x];
    for (int k = 0; k < 4; k++) {
        int idx = base + t * 4 + k;
        if (idx < NN) {
            int v = rs[idx] + off;
            rs[idx] = v;
            cursor[idx] = v;
        }
    }
    if (blockIdx.x == 0 && t == 0) rs[NN] = NE;
}

// ---------------- bucket edges by dst (also precompute edge weights) ----------------

__global__ __launch_bounds__(256) void bucket_kernel(const int* __restrict__ src, const int* __restrict__ dst,
                                                     const float* __restrict__ dinv,
                                                     int* __restrict__ cursor,
                                                     int* __restrict__ esrc, float* __restrict__ ewt) {
    int e = blockIdx.x * blockDim.x + threadIdx.x;
    if (e < NE) {
        int s = src[e], d = dst[e];
        int pos = atomicAdd(&cursor[d], 1);
        esrc[pos] = s;
        ewt[pos] = dinv[s] * dinv[d];
    }
}

// ---------------- layer 0 part A: aggregate raw x (7-dim) -> xa [NN,8] ----------------

__global__ __launch_bounds__(256) void xagg_kernel(const float* __restrict__ x,
                                                   const int* __restrict__ rs,
                                                   const int* __restrict__ esrc,
                                                   const float* __restrict__ ewt,
                                                   const float* __restrict__ dinv,
                                                   float* __restrict__ xa) {
    int t = blockIdx.x * blockDim.x + threadIdx.x;
    int f = t & 7;
    int n = t >> 3;
    if (n >= NN) return;
    float acc = 0.f;
    if (f < 7) {
        float di = dinv[n];
        acc = x[n * 7 + f] * di * di;
        int e0 = rs[n], e1 = rs[n + 1];
        int e = e0;
        for (; e + 1 < e1; e += 2) {
            int s0 = esrc[e], s1 = esrc[e + 1];
            float w0 = ewt[e], w1 = ewt[e + 1];
            float a0 = x[s0 * 7 + f];
            float a1 = x[s1 * 7 + f];
            acc = fmaf(a0, w0, acc);
            acc = fmaf(a1, w1, acc);
        }
        if (e < e1) acc = fmaf(x[esrc[e] * 7 + f], ewt[e], acc);
    }
    xa[n * 8 + f] = acc;
}

// ---------------- layer 0 part B: xa @ W0 + b -> BN -> ReLU -> out ----------------

__global__ __launch_bounds__(256) void l0_transform(const float* __restrict__ xa,
                                                    const float* __restrict__ W,
                                                    const float* __restrict__ b,
                                                    const float* __restrict__ gamma,
                                                    const float* __restrict__ beta,
                                                    const float* __restrict__ mean,
                                                    const float* __restrict__ var,
                                                    float* __restrict__ out) {
    int j = threadIdx.x & 127;
    int half = threadIdx.x >> 7;
    float w[7];
#pragma unroll
    for (int k = 0; k < 7; k++) w[k] = W[k * HID + j];
    float bj = b[j];
    float scale = gamma[j] * rsqrtf(var[j] + BN_EPS);
    float mj = mean[j], bt = beta[j];
    __shared__ float s[32][8];
    int r = threadIdx.x >> 3, f = threadIdx.x & 7;
    for (int n0 = blockIdx.x * 32; n0 < NN; n0 += gridDim.x * 32) {
        __syncthreads();
        s[r][f] = xa[(n0 + r) * 8 + f];
        __syncthreads();
        int mend = half * 16 + 16;
        for (int m = half * 16; m < mend; m++) {
            float o = bj;
#pragma unroll
            for (int k = 0; k < 7; k++) o = fmaf(s[m][k], w[k], o);
            out[(size_t)(n0 + m) * HID + j] = fmaxf(fmaf(o - mj, scale, bt), 0.f);
        }
    }
}

// ---------------- layers 1/2 matmul: h [NN,128] @ W [128,128] -> hl ----------------
// v3: W fully LDS-resident (64 KB), staged ONCE per block; 512 persistent
// blocks (2/CU = 160 KB LDS) grid-stride over 32-row tiles (16 KB h stage,
// register-prefetched). Thread (tx 0..31, ty 0..7): 4 rows x 4 cols micro-tile.
// LDS reads per wave per k4: 4 h-broadcasts (2 uniq addrs, free) + 4 W-reads
// (16B lane stride, 2-way = free) for 64 FMAs -> VALU-bound.

__global__ __launch_bounds__(256) void gcn_mm128(const float* __restrict__ hin,
                                                 const float* __restrict__ W,
                                                 float* __restrict__ hl) {
    __shared__ float4 wbuf[128 * 32];  // [k][c4]  64 KB
    __shared__ float4 hbuf[32 * 32];   // [r][k4]  16 KB
    int t = threadIdx.x;
    int tx = t & 31;
    int ty = t >> 5;
    const float4* hin4 = (const float4*)hin;
    const float4* W4   = (const float4*)W;
    float4* out4       = (float4*)hl;

    // stage all of W once (linear, coalesced)
#pragma unroll
    for (int i = 0; i < 16; i++) wbuf[t + i * 256] = W4[t + i * 256];

    int tile = blockIdx.x;
    float4 ph[4];
    if (tile < MM_TILES) {
#pragma unroll
        for (int i = 0; i < 4; i++) {
            int f = t + i * 256;  // 0..1023: r = f>>5, k4 = f&31
            ph[i] = hin4[(size_t)(tile * 32 + (f >> 5)) * 32 + (f & 31)];
        }
    }

    for (; tile < MM_TILES; tile += gridDim.x) {
        __syncthreads();  // wbuf ready (iter 0) / previous compute done with hbuf
#pragma unroll
        for (int i = 0; i < 4; i++) hbuf[t + i * 256] = ph[i];
        __syncthreads();

        int nt = tile + gridDim.x;  // prefetch next tile's h during compute
        if (nt < MM_TILES) {
#pragma unroll
            for (int i = 0; i < 4; i++) {
                int f = t + i * 256;
                ph[i] = hin4[(size_t)(nt * 32 + (f >> 5)) * 32 + (f & 31)];
            }
        }

        float4 acc[4];
#pragma unroll
        for (int rr = 0; rr < 4; rr++) acc[rr] = make_float4(0.f, 0.f, 0.f, 0.f);

#pragma unroll 8
        for (int k4 = 0; k4 < 32; k4++) {
            float4 hv[4];
#pragma unroll
            for (int rr = 0; rr < 4; rr++) hv[rr] = hbuf[(ty * 4 + rr) * 32 + k4];
#pragma unroll
            for (int kk = 0; kk < 4; kk++) {
                float4 wv = wbuf[(k4 * 4 + kk) * 32 + tx];
#pragma unroll
                for (int rr = 0; rr < 4; rr++) {
                    float hs = ((const float*)&hv[rr])[kk];
                    acc[rr].x = fmaf(hs, wv.x, acc[rr].x);
                    acc[rr].y = fmaf(hs, wv.y, acc[rr].y);
                    acc[rr].z = fmaf(hs, wv.z, acc[rr].z);
                    acc[rr].w = fmaf(hs, wv.w, acc[rr].w);
                }
            }
        }

#pragma unroll
        for (int rr = 0; rr < 4; rr++)
            out4[(size_t)(tile * 32 + ty * 4 + rr) * 32 + tx] = acc[rr];
    }
}

// ---------------- gather-aggregate + self-loop + bias + BN + ReLU ----------------

__global__ __launch_bounds__(256) void gather_bn(const float* __restrict__ hl,
                                                 const int* __restrict__ rs,
                                                 const int* __restrict__ esrc,
                                                 const float* __restrict__ ewt,
                                                 const float* __restrict__ dinv,
                                                 const float* __restrict__ b,
                                                 const float* __restrict__ gamma,
                                                 const float* __restrict__ beta,
                                                 const float* __restrict__ mean,
                                                 const float* __restrict__ var,
                                                 float* __restrict__ out) {
    int t = blockIdx.x * blockDim.x + threadIdx.x;
    int lane = t & 31;
    int n = t >> 5;
    if (n >= NN) return;
    const float4* hl4 = (const float4*)hl;
    float di = dinv[n];
    float4 self = hl4[(size_t)n * 32 + lane];
    float4 bb = ((const float4*)b)[lane];
    float dsq = di * di;
    float4 acc;
    acc.x = fmaf(self.x, dsq, bb.x);
    acc.y = fmaf(self.y, dsq, bb.y);
    acc.z = fmaf(self.z, dsq, bb.z);
    acc.w = fmaf(self.w, dsq, bb.w);
    int e0 = rs[n], e1 = rs[n + 1];
    int e = e0;
    for (; e + 1 < e1; e += 2) {
        int s0 = esrc[e], s1 = esrc[e + 1];
        float w0 = ewt[e], w1 = ewt[e + 1];
        float4 v0 = hl4[(size_t)s0 * 32 + lane];
        float4 v1 = hl4[(size_t)s1 * 32 + lane];
        acc.x = fmaf(v0.x, w0, acc.x); acc.y = fmaf(v0.y, w0, acc.y);
        acc.z = fmaf(v0.z, w0, acc.z); acc.w = fmaf(v0.w, w0, acc.w);
        acc.x = fmaf(v1.x, w1, acc.x); acc.y = fmaf(v1.y, w1, acc.y);
        acc.z = fmaf(v1.z, w1, acc.z); acc.w = fmaf(v1.w, w1, acc.w);
    }
    if (e < e1) {
        int s0 = esrc[e];
        float w0 = ewt[e];
        float4 v0 = hl4[(size_t)s0 * 32 + lane];
        acc.x = fmaf(v0.x, w0, acc.x); acc.y = fmaf(v0.y, w0, acc.y);
        acc.z = fmaf(v0.z, w0, acc.z); acc.w = fmaf(v0.w, w0, acc.w);
    }
    float4 ga = ((const float4*)gamma)[lane];
    float4 be = ((const float4*)beta)[lane];
    float4 me = ((const float4*)mean)[lane];
    float4 va = ((const float4*)var)[lane];
    float4 o;
    o.x = fmaxf(fmaf(acc.x - me.x, ga.x * rsqrtf(va.x + BN_EPS), be.x), 0.f);
    o.y = fmaxf(fmaf(acc.y - me.y, ga.y * rsqrtf(va.y + BN_EPS), be.y), 0.f);
    o.z = fmaxf(fmaf(acc.z - me.z, ga.z * rsqrtf(va.z + BN_EPS), be.z), 0.f);
    o.w = fmaxf(fmaf(acc.w - me.w, ga.w * rsqrtf(va.w + BN_EPS), be.w), 0.f);
    ((float4*)out)[(size_t)n * 32 + lane] = o;
}

// ---------------- global mean pool (batch is sorted) ----------------

__global__ __launch_bounds__(1024) void pool_kernel(const float* __restrict__ h,
                                                    const int* __restrict__ batch,
                                                    float* __restrict__ lig) {
    int g = blockIdx.x;
    int lane = threadIdx.x & 31;   // float4 index within feature row
    int row = threadIdx.x >> 5;    // 0..31
    __shared__ int se[2];
    if (threadIdx.x < 2) {
        int target = g + threadIdx.x;
        int lo = 0, hi = NN;
        while (lo < hi) {
            int mid = (lo + hi) >> 1;
            if (batch[mid] < target) lo = mid + 1; else hi = mid;
        }
        se[threadIdx.x] = lo;
    }
    __syncthreads();
    int start = se[0], end = se[1];
    const float4* h4 = (const float4*)h;
    float4 acc = make_float4(0.f, 0.f, 0.f, 0.f);
    for (int n = start + row; n < end; n += 32) {
        float4 v = h4[(size_t)n * 32 + lane];
        acc.x += v.x; acc.y += v.y; acc.z += v.z; acc.w += v.w;
    }
    __shared__ float4 part[32][32];
    part[row][lane] = acc;
    __syncthreads();
#pragma unroll
    for (int off = 16; off >= 1; off >>= 1) {
        if (row < off) {
            float4 a = part[row][lane];
            float4 c = part[row + off][lane];
            a.x += c.x; a.y += c.y; a.z += c.z; a.w += c.w;
            part[row][lane] = a;
        }
        __syncthreads();
    }
    if (row == 0) {
        float inv = 1.0f / fmaxf((float)(end - start), 1.0f);
        float4 a = part[0][lane];
        a.x *= inv; a.y *= inv; a.z *= inv; a.w *= inv;
        ((float4*)lig)[g * 32 + lane] = a;
    }
}

// ---------------- pocket MLP: 28 -> 64 -> 64 ----------------

__global__ __launch_bounds__(64) void pocket_kernel(const float* __restrict__ pocket,
                                                    const float* __restrict__ pw1,
                                                    const float* __restrict__ pb1,
                                                    const float* __restrict__ pw2,
                                                    const float* __restrict__ pb2,
                                                    float* __restrict__ p) {
    int j = threadIdx.x;
    __shared__ float t1[64];
    float acc = pb1[j];
    for (int k = 0; k < 28; k++) acc = fmaf(pocket[k], pw1[k * 64 + j], acc);
    t1[j] = fmaxf(acc, 0.f);
    __syncthreads();
    float acc2 = pb2[j];
    for (int k = 0; k < 64; k++) acc2 = fmaf(t1[k], pw2[k * 64 + j], acc2);
    p[j] = acc2;
}

// ---------------- classifier: concat(lig, p) -> 96 -> 1 ----------------

__global__ __launch_bounds__(96) void cls_kernel(const float* __restrict__ lig,
                                                 const float* __restrict__ p,
                                                 const float* __restrict__ cw1,
                                                 const float* __restrict__ cb1,
                                                 const float* __restrict__ cw2,
                                                 const float* __restrict__ cb2,
                                                 float* __restrict__ out) {
    int g = blockIdx.x;
    int j = threadIdx.x;
    __shared__ float emb[192];
    __shared__ float hid[96];
    for (int k = j; k < HID; k += 96) emb[k] = lig[g * HID + k];
    for (int k = j; k < 64; k += 96) emb[HID + k] = p[k];
    __syncthreads();
    float acc = cb1[j];
    for (int k = 0; k < 192; k++) acc = fmaf(emb[k], cw1[k * 96 + j], acc);
    hid[j] = fmaxf(acc, 0.f) * cw2[j];
    __syncthreads();
    if (j == 0) {
        float s = cb2[0];
        for (int k = 0; k < 96; k++) s += hid[k];
        out[g] = s;
    }
}

extern "C" void kernel_launch(void* const* d_in, const int* in_sizes, int n_in,
                              void* d_out, int out_size, void* d_ws, size_t ws_size,
                              hipStream_t stream) {
    const float* x        = (const float*)d_in[0];
    const int*   eidx     = (const int*)d_in[1];
    const int*   batch    = (const int*)d_in[2];
    const float* pocket   = (const float*)d_in[3];
    const float* W0 = (const float*)d_in[4];
    const float* b0 = (const float*)d_in[5];
    const float* W1 = (const float*)d_in[6];
    const float* b1 = (const float*)d_in[7];
    const float* W2 = (const float*)d_in[8];
    const float* b2 = (const float*)d_in[9];
    const float* bn_gamma = (const float*)d_in[10];
    const float* bn_beta  = (const float*)d_in[11];
    const float* bn_mean  = (const float*)d_in[12];
    const float* bn_var   = (const float*)d_in[13];
    const float* pw1 = (const float*)d_in[14]; const float* pb1 = (const float*)d_in[15];
    const float* pw2 = (const float*)d_in[16]; const float* pb2 = (const float*)d_in[17];
    const float* cw1 = (const float*)d_in[18]; const float* cb1 = (const float*)d_in[19];
    const float* cw2 = (const float*)d_in[20]; const float* cb2 = (const float*)d_in[21];
    float* out = (float*)d_out;

    // Workspace layout (4-byte units, A/B 16B-aligned):
    float* ws   = (float*)d_ws;
    float* dinv = ws;                                   // NN
    int*   cnt  = (int*)(ws + NN);                      // NN (hist, then cursor)
    int*   rs   = cnt + NN;                             // NN+1
    int*   tsum = rs + NN + 1;                          // 128
    int*   esrc = tsum + 128;                           // NE
    float* ewt  = (float*)(esrc + NE);                  // NE
    float* xa   = ewt + NE;                             // NN*8
    size_t head = (size_t)NN * 2 + (NN + 1) + 128 + (size_t)NE * 2 + (size_t)NN * 8;
    head = (head + 3) & ~(size_t)3;                     // 16B align
    float* A    = ws + head;                            // NN*HID
    float* B    = A + (size_t)NN * HID;                 // NN*HID
    float* lig  = B + (size_t)NN * HID;                 // NG*HID
    float* pv   = lig + (size_t)NG * HID;               // 64

    const int* srcp = eidx;
    const int* dstp = eidx + NE;

    // ---- build CSR (by dst) + dinv + edge weights ----
    hipMemsetAsync(cnt, 0, NN * sizeof(int), stream);
    hist_kernel<<<(NE + 255) / 256, 256, 0, stream>>>(dstp, cnt);
    dinv_kernel<<<(NN + 255) / 256, 256, 0, stream>>>(cnt, dinv);
    scan_a<<<NTILES, 256, 0, stream>>>(cnt, rs, tsum);
    scan_b<<<1, 128, 0, stream>>>(tsum);
    scan_c<<<NTILES, 256, 0, stream>>>(rs, tsum, cnt);  // cnt becomes cursor
    bucket_kernel<<<(NE + 255) / 256, 256, 0, stream>>>(srcp, dstp, dinv, cnt, esrc, ewt);

    // ---- layer 0: aggregate x, then transform (A = relu(bn(agg(x) @ W0 + b0))) ----
    xagg_kernel<<<(NN * 8 + 255) / 256, 256, 0, stream>>>(x, rs, esrc, ewt, dinv, xa);
    l0_transform<<<2048, 256, 0, stream>>>(xa, W0, b0,
                                           bn_gamma + 0 * HID, bn_beta + 0 * HID,
                                           bn_mean + 0 * HID, bn_var + 0 * HID, A);

    const int MM_BLOCKS = 512;  // 2 blocks/CU (80 KB LDS each), persistent

    // ---- layer 1 ----
    gcn_mm128<<<MM_BLOCKS, 256, 0, stream>>>(A, W1, B);
    gather_bn<<<(NN * 32 + 255) / 256, 256, 0, stream>>>(B, rs, esrc, ewt, dinv, b1,
                                                         bn_gamma + 1 * HID, bn_beta + 1 * HID,
                                                         bn_mean + 1 * HID, bn_var + 1 * HID, A);
    // ---- layer 2 ----
    gcn_mm128<<<MM_BLOCKS, 256, 0, stream>>>(A, W2, B);
    gather_bn<<<(NN * 32 + 255) / 256, 256, 0, stream>>>(B, rs, esrc, ewt, dinv, b2,
                                                         bn_gamma + 2 * HID, bn_beta + 2 * HID,
                                                         bn_mean + 2 * HID, bn_var + 2 * HID, A);

    // pool -> lig
    pool_kernel<<<NG, 1024, 0, stream>>>(A, batch, lig);
    // pocket MLP
    pocket_kernel<<<1, 64, 0, stream>>>(pocket, pw1, pb1, pw2, pb2, pv);
    // classifier
    cls_kernel<<<NG, 96, 0, stream>>>(lig, pv, cw1, cb1, cw2, cb2, out);
}

// Round 8
// 455.515 us; speedup vs baseline: 1.0417x; 1.0417x over previous
//
#include <hip/hip_runtime.h>

// Problem constants (match reference setup_inputs)
#define NN 100000
#define NE 600000
#define NG 256
#define HID 128
#define BN_EPS 1e-5f

#define SCAN_TILE 1024
#define NTILES ((NN + SCAN_TILE - 1) / SCAN_TILE)  // 98

typedef __attribute__((ext_vector_type(8))) short short8;
typedef __attribute__((ext_vector_type(4))) float float4v;

// bf16 round-to-nearest-even helpers
__device__ __forceinline__ unsigned short f2bf_rn(float f) {
    unsigned u = __float_as_uint(f);
    unsigned r = u + 0x7FFFu + ((u >> 16) & 1u);
    return (unsigned short)(r >> 16);
}
__device__ __forceinline__ float bf2f(unsigned short h) {
    return __uint_as_float((unsigned)h << 16);
}

// ---------------- histogram of dst (in-degree) ----------------

__global__ __launch_bounds__(256) void hist_kernel(const int* __restrict__ dst, int* __restrict__ cnt) {
    int e = blockIdx.x * blockDim.x + threadIdx.x;
    if (e < NE) atomicAdd(&cnt[dst[e]], 1);
}

__global__ __launch_bounds__(256) void dinv_kernel(const int* __restrict__ cnt, float* __restrict__ dinv) {
    int n = blockIdx.x * blockDim.x + threadIdx.x;
    if (n < NN) dinv[n] = rsqrtf((float)cnt[n] + 1.0f);
}

// ---------------- 2-level exclusive scan of cnt -> row_start ----------------

__global__ __launch_bounds__(256) void scan_a(const int* __restrict__ cnt, int* __restrict__ rs,
                                              int* __restrict__ tsum) {
    __shared__ int s[256];
    int t = threadIdx.x;
    int base = blockIdx.x * SCAN_TILE;
    int idx = base + t * 4;
    int v0 = (idx + 0 < NN) ? cnt[idx + 0] : 0;
    int v1 = (idx + 1 < NN) ? cnt[idx + 1] : 0;
    int v2 = (idx + 2 < NN) ? cnt[idx + 2] : 0;
    int v3 = (idx + 3 < NN) ? cnt[idx + 3] : 0;
    int local = v0 + v1 + v2 + v3;
    s[t] = local;
    __syncthreads();
    for (int off = 1; off < 256; off <<= 1) {
        int x = (t >= off) ? s[t - off] : 0;
        __syncthreads();
        s[t] += x;
        __syncthreads();
    }
    int pre = s[t] - local;  // exclusive prefix within tile
    if (t == 255) tsum[blockIdx.x] = s[255];
    if (idx + 0 < NN) rs[idx + 0] = pre; pre += v0;
    if (idx + 1 < NN) rs[idx + 1] = pre; pre += v1;
    if (idx + 2 < NN) rs[idx + 2] = pre; pre += v2;
    if (idx + 3 < NN) rs[idx + 3] = pre;
}

__global__ __launch_bounds__(128) void scan_b(int* __restrict__ tsum) {
    __shared__ int s[128];
    int t = threadIdx.x;
    int v = (t < NTILES) ? tsum[t] : 0;
    s[t] = v;
    __syncthreads();
    for (int off = 1; off < 128; off <<= 1) {
        int x = (t >= off) ? s[t - off] : 0;
        __syncthreads();
        s[t] += x;
        __syncthreads();
    }
    if (t < NTILES) tsum[t] = s[t] - v;  // exclusive
}

__global__ __launch_bounds__(256) void scan_c(int* __restrict__ rs, const int* __restrict__ tsum,
                                              int* __restrict__ cursor) {
    int t = threadIdx.x;
    int base = blockIdx.x * SCAN_TILE;
    int off = tsum[blockIdx.x];
    for (int k = 0; k < 4; k++) {
        int idx = base + t * 4 + k;
        if (idx < NN) {
            int v = rs[idx] + off;
            rs[idx] = v;
            cursor[idx] = v;
        }
    }
    if (blockIdx.x == 0 && t == 0) rs[NN] = NE;
}

// ---------------- bucket edges by dst (also precompute edge weights) ----------------

__global__ __launch_bounds__(256) void bucket_kernel(const int* __restrict__ src, const int* __restrict__ dst,
                                                     const float* __restrict__ dinv,
                                                     int* __restrict__ cursor,
                                                     int* __restrict__ esrc, float* __restrict__ ewt) {
    int e = blockIdx.x * blockDim.x + threadIdx.x;
    if (e < NE) {
        int s = src[e], d = dst[e];
        int pos = atomicAdd(&cursor[d], 1);
        esrc[pos] = s;
        ewt[pos] = dinv[s] * dinv[d];
    }
}

// ---------------- split W1/W2 into bf16 hi/lo, transposed to [n][k] ----------------

__global__ __launch_bounds__(256) void wconv_kernel(const float* __restrict__ W1, const float* __restrict__ W2,
                                                    unsigned short* __restrict__ w1hi, unsigned short* __restrict__ w1lo,
                                                    unsigned short* __restrict__ w2hi, unsigned short* __restrict__ w2lo) {
    int t = blockIdx.x * blockDim.x + threadIdx.x;
    if (t >= HID * HID) return;
    int k = t >> 7, n = t & 127;      // W[k][n]
    int to = n * HID + k;             // Wt[n][k]
    float v1 = W1[t];
    unsigned short h1 = f2bf_rn(v1);
    w1hi[to] = h1;
    w1lo[to] = f2bf_rn(v1 - bf2f(h1));
    float v2 = W2[t];
    unsigned short h2 = f2bf_rn(v2);
    w2hi[to] = h2;
    w2lo[to] = f2bf_rn(v2 - bf2f(h2));
}

// ---------------- layer 0 part A: aggregate raw x (7-dim) -> xa [NN,8] ----------------

__global__ __launch_bounds__(256) void xagg_kernel(const float* __restrict__ x,
                                                   const int* __restrict__ rs,
                                                   const int* __restrict__ esrc,
                                                   const float* __restrict__ ewt,
                                                   const float* __restrict__ dinv,
                                                   float* __restrict__ xa) {
    int t = blockIdx.x * blockDim.x + threadIdx.x;
    int f = t & 7;
    int n = t >> 3;
    if (n >= NN) return;
    float acc = 0.f;
    if (f < 7) {
        float di = dinv[n];
        acc = x[n * 7 + f] * di * di;
        int e0 = rs[n], e1 = rs[n + 1];
        int e = e0;
        for (; e + 1 < e1; e += 2) {
            int s0 = esrc[e], s1 = esrc[e + 1];
            float w0 = ewt[e], w1 = ewt[e + 1];
            float a0 = x[s0 * 7 + f];
            float a1 = x[s1 * 7 + f];
            acc = fmaf(a0, w0, acc);
            acc = fmaf(a1, w1, acc);
        }
        if (e < e1) acc = fmaf(x[esrc[e] * 7 + f], ewt[e], acc);
    }
    xa[n * 8 + f] = acc;
}

// ---------------- layer 0 part B: xa @ W0 + b -> BN -> ReLU -> bf16 hi/lo ----------------

__global__ __launch_bounds__(256) void l0_transform(const float* __restrict__ xa,
                                                    const float* __restrict__ W,
                                                    const float* __restrict__ b,
                                                    const float* __restrict__ gamma,
                                                    const float* __restrict__ beta,
                                                    const float* __restrict__ mean,
                                                    const float* __restrict__ var,
                                                    unsigned short* __restrict__ ohi,
                                                    unsigned short* __restrict__ olo) {
    int j = threadIdx.x & 127;
    int half = threadIdx.x >> 7;
    float w[7];
#pragma unroll
    for (int k = 0; k < 7; k++) w[k] = W[k * HID + j];
    float bj = b[j];
    float scale = gamma[j] * rsqrtf(var[j] + BN_EPS);
    float mj = mean[j], bt = beta[j];
    __shared__ float s[32][8];
    int r = threadIdx.x >> 3, f = threadIdx.x & 7;
    for (int n0 = blockIdx.x * 32; n0 < NN; n0 += gridDim.x * 32) {
        __syncthreads();
        s[r][f] = xa[(n0 + r) * 8 + f];
        __syncthreads();
        int mend = half * 16 + 16;
        for (int m = half * 16; m < mend; m++) {
            float o = bj;
#pragma unroll
            for (int k = 0; k < 7; k++) o = fmaf(s[m][k], w[k], o);
            float v = fmaxf(fmaf(o - mj, scale, bt), 0.f);
            unsigned short h = f2bf_rn(v);
            size_t idx = (size_t)(n0 + m) * HID + j;
            ohi[idx] = h;
            olo[idx] = f2bf_rn(v - bf2f(h));
        }
    }
}

// ---------------- layers 1/2 matmul via MFMA (split-bf16 fp32-accurate) ----------------
// out[m][n] = sum_k h[m][k] * W[k][n], h = Ahi+Alo, W = Whi+Wlo (Wt stored [n][k]).
// Block = 32 rows x 128 cols; 4 waves, each wave 2x2 tiles of 16x16.
// A frag: [m=lane&15][k=quad*8+j]; B frag: [k=quad*8+j][n=lane&15] (from Wt[n][k]);
// C/D: col=lane&15, row=quad*4+reg.

__global__ __launch_bounds__(256) void mm_mfma(const unsigned short* __restrict__ Ahi,
                                               const unsigned short* __restrict__ Alo,
                                               const unsigned short* __restrict__ Whi,
                                               const unsigned short* __restrict__ Wlo,
                                               float* __restrict__ out) {
    int wave = threadIdx.x >> 6;
    int lane = threadIdx.x & 63;
    int mrow = lane & 15;
    int quad = lane >> 4;
    int m0 = blockIdx.x * 32;
    int n0 = wave * 32;

    short8 bh[2][4], bl[2][4];
#pragma unroll
    for (int ct = 0; ct < 2; ct++) {
#pragma unroll
        for (int kc = 0; kc < 4; kc++) {
            size_t off = (size_t)(n0 + ct * 16 + mrow) * HID + kc * 32 + quad * 8;
            bh[ct][kc] = *(const short8*)(Whi + off);
            bl[ct][kc] = *(const short8*)(Wlo + off);
        }
    }

    float4v acc[2][2];
#pragma unroll
    for (int rt = 0; rt < 2; rt++)
#pragma unroll
        for (int ct = 0; ct < 2; ct++) {
            acc[rt][ct].x = 0.f; acc[rt][ct].y = 0.f;
            acc[rt][ct].z = 0.f; acc[rt][ct].w = 0.f;
        }

#pragma unroll
    for (int kc = 0; kc < 4; kc++) {
#pragma unroll
        for (int rt = 0; rt < 2; rt++) {
            size_t aoff = (size_t)(m0 + rt * 16 + mrow) * HID + kc * 32 + quad * 8;
            short8 ah = *(const short8*)(Ahi + aoff);
            short8 al = *(const short8*)(Alo + aoff);
#pragma unroll
            for (int ct = 0; ct < 2; ct++) {
                acc[rt][ct] = __builtin_amdgcn_mfma_f32_16x16x32_bf16(ah, bh[ct][kc], acc[rt][ct], 0, 0, 0);
                acc[rt][ct] = __builtin_amdgcn_mfma_f32_16x16x32_bf16(ah, bl[ct][kc], acc[rt][ct], 0, 0, 0);
                acc[rt][ct] = __builtin_amdgcn_mfma_f32_16x16x32_bf16(al, bh[ct][kc], acc[rt][ct], 0, 0, 0);
                acc[rt][ct] = __builtin_amdgcn_mfma_f32_16x16x32_bf16(al, bl[ct][kc], acc[rt][ct], 0, 0, 0);
            }
        }
    }

#pragma unroll
    for (int rt = 0; rt < 2; rt++) {
#pragma unroll
        for (int ct = 0; ct < 2; ct++) {
            int col = n0 + ct * 16 + mrow;
#pragma unroll
            for (int r = 0; r < 4; r++) {
                int row = m0 + rt * 16 + quad * 4 + r;
                out[(size_t)row * HID + col] = acc[rt][ct][r];
            }
        }
    }
}

// ---------------- gather-aggregate + self-loop + bias + BN + ReLU ----------------
// BF16OUT: write planar bf16 hi/lo (feeds next mm_mfma); else fp32 (feeds pool).

template <bool BF16OUT>
__global__ __launch_bounds__(256) void gather_bn_t(const float* __restrict__ hl,
                                                   const int* __restrict__ rs,
                                                   const int* __restrict__ esrc,
                                                   const float* __restrict__ ewt,
                                                   const float* __restrict__ dinv,
                                                   const float* __restrict__ b,
                                                   const float* __restrict__ gamma,
                                                   const float* __restrict__ beta,
                                                   const float* __restrict__ mean,
                                                   const float* __restrict__ var,
                                                   float* __restrict__ outf,
                                                   unsigned short* __restrict__ ohi,
                                                   unsigned short* __restrict__ olo) {
    int t = blockIdx.x * blockDim.x + threadIdx.x;
    int lane = t & 31;
    int n = t >> 5;
    if (n >= NN) return;
    const float4* hl4 = (const float4*)hl;
    float di = dinv[n];
    float4 self = hl4[(size_t)n * 32 + lane];
    float4 bb = ((const float4*)b)[lane];
    float dsq = di * di;
    float4 acc;
    acc.x = fmaf(self.x, dsq, bb.x);
    acc.y = fmaf(self.y, dsq, bb.y);
    acc.z = fmaf(self.z, dsq, bb.z);
    acc.w = fmaf(self.w, dsq, bb.w);
    int e0 = rs[n], e1 = rs[n + 1];
    int e = e0;
    for (; e + 1 < e1; e += 2) {
        int s0 = esrc[e], s1 = esrc[e + 1];
        float w0 = ewt[e], w1 = ewt[e + 1];
        float4 v0 = hl4[(size_t)s0 * 32 + lane];
        float4 v1 = hl4[(size_t)s1 * 32 + lane];
        acc.x = fmaf(v0.x, w0, acc.x); acc.y = fmaf(v0.y, w0, acc.y);
        acc.z = fmaf(v0.z, w0, acc.z); acc.w = fmaf(v0.w, w0, acc.w);
        acc.x = fmaf(v1.x, w1, acc.x); acc.y = fmaf(v1.y, w1, acc.y);
        acc.z = fmaf(v1.z, w1, acc.z); acc.w = fmaf(v1.w, w1, acc.w);
    }
    if (e < e1) {
        int s0 = esrc[e];
        float w0 = ewt[e];
        float4 v0 = hl4[(size_t)s0 * 32 + lane];
        acc.x = fmaf(v0.x, w0, acc.x); acc.y = fmaf(v0.y, w0, acc.y);
        acc.z = fmaf(v0.z, w0, acc.z); acc.w = fmaf(v0.w, w0, acc.w);
    }
    float4 ga = ((const float4*)gamma)[lane];
    float4 be = ((const float4*)beta)[lane];
    float4 me = ((const float4*)mean)[lane];
    float4 va = ((const float4*)var)[lane];
    float4 o;
    o.x = fmaxf(fmaf(acc.x - me.x, ga.x * rsqrtf(va.x + BN_EPS), be.x), 0.f);
    o.y = fmaxf(fmaf(acc.y - me.y, ga.y * rsqrtf(va.y + BN_EPS), be.y), 0.f);
    o.z = fmaxf(fmaf(acc.z - me.z, ga.z * rsqrtf(va.z + BN_EPS), be.z), 0.f);
    o.w = fmaxf(fmaf(acc.w - me.w, ga.w * rsqrtf(va.w + BN_EPS), be.w), 0.f);
    if (BF16OUT) {
        ushort4 hi4, lo4;
        hi4.x = f2bf_rn(o.x); lo4.x = f2bf_rn(o.x - bf2f(hi4.x));
        hi4.y = f2bf_rn(o.y); lo4.y = f2bf_rn(o.y - bf2f(hi4.y));
        hi4.z = f2bf_rn(o.z); lo4.z = f2bf_rn(o.z - bf2f(hi4.z));
        hi4.w = f2bf_rn(o.w); lo4.w = f2bf_rn(o.w - bf2f(hi4.w));
        ((ushort4*)ohi)[(size_t)n * 32 + lane] = hi4;
        ((ushort4*)olo)[(size_t)n * 32 + lane] = lo4;
    } else {
        ((float4*)outf)[(size_t)n * 32 + lane] = o;
    }
}

// ---------------- global mean pool (batch is sorted) ----------------

__global__ __launch_bounds__(1024) void pool_kernel(const float* __restrict__ h,
                                                    const int* __restrict__ batch,
                                                    float* __restrict__ lig) {
    int g = blockIdx.x;
    int lane = threadIdx.x & 31;   // float4 index within feature row
    int row = threadIdx.x >> 5;    // 0..31
    __shared__ int se[2];
    if (threadIdx.x < 2) {
        int target = g + threadIdx.x;
        int lo = 0, hi = NN;
        while (lo < hi) {
            int mid = (lo + hi) >> 1;
            if (batch[mid] < target) lo = mid + 1; else hi = mid;
        }
        se[threadIdx.x] = lo;
    }
    __syncthreads();
    int start = se[0], end = se[1];
    const float4* h4 = (const float4*)h;
    float4 acc = make_float4(0.f, 0.f, 0.f, 0.f);
    for (int n = start + row; n < end; n += 32) {
        float4 v = h4[(size_t)n * 32 + lane];
        acc.x += v.x; acc.y += v.y; acc.z += v.z; acc.w += v.w;
    }
    __shared__ float4 part[32][32];
    part[row][lane] = acc;
    __syncthreads();
#pragma unroll
    for (int off = 16; off >= 1; off >>= 1) {
        if (row < off) {
            float4 a = part[row][lane];
            float4 c = part[row + off][lane];
            a.x += c.x; a.y += c.y; a.z += c.z; a.w += c.w;
            part[row][lane] = a;
        }
        __syncthreads();
    }
    if (row == 0) {
        float inv = 1.0f / fmaxf((float)(end - start), 1.0f);
        float4 a = part[0][lane];
        a.x *= inv; a.y *= inv; a.z *= inv; a.w *= inv;
        ((float4*)lig)[g * 32 + lane] = a;
    }
}

// ---------------- pocket MLP: 28 -> 64 -> 64 ----------------

__global__ __launch_bounds__(64) void pocket_kernel(const float* __restrict__ pocket,
                                                    const float* __restrict__ pw1,
                                                    const float* __restrict__ pb1,
                                                    const float* __restrict__ pw2,
                                                    const float* __restrict__ pb2,
                                                    float* __restrict__ p) {
    int j = threadIdx.x;
    __shared__ float t1[64];
    float acc = pb1[j];
    for (int k = 0; k < 28; k++) acc = fmaf(pocket[k], pw1[k * 64 + j], acc);
    t1[j] = fmaxf(acc, 0.f);
    __syncthreads();
    float acc2 = pb2[j];
    for (int k = 0; k < 64; k++) acc2 = fmaf(t1[k], pw2[k * 64 + j], acc2);
    p[j] = acc2;
}

// ---------------- classifier: concat(lig, p) -> 96 -> 1 ----------------

__global__ __launch_bounds__(96) void cls_kernel(const float* __restrict__ lig,
                                                 const float* __restrict__ p,
                                                 const float* __restrict__ cw1,
                                                 const float* __restrict__ cb1,
                                                 const float* __restrict__ cw2,
                                                 const float* __restrict__ cb2,
                                                 float* __restrict__ out) {
    int g = blockIdx.x;
    int j = threadIdx.x;
    __shared__ float emb[192];
    __shared__ float hid[96];
    for (int k = j; k < HID; k += 96) emb[k] = lig[g * HID + k];
    for (int k = j; k < 64; k += 96) emb[HID + k] = p[k];
    __syncthreads();
    float acc = cb1[j];
    for (int k = 0; k < 192; k++) acc = fmaf(emb[k], cw1[k * 96 + j], acc);
    hid[j] = fmaxf(acc, 0.f) * cw2[j];
    __syncthreads();
    if (j == 0) {
        float s = cb2[0];
        for (int k = 0; k < 96; k++) s += hid[k];
        out[g] = s;
    }
}

extern "C" void kernel_launch(void* const* d_in, const int* in_sizes, int n_in,
                              void* d_out, int out_size, void* d_ws, size_t ws_size,
                              hipStream_t stream) {
    const float* x        = (const float*)d_in[0];
    const int*   eidx     = (const int*)d_in[1];
    const int*   batch    = (const int*)d_in[2];
    const float* pocket   = (const float*)d_in[3];
    const float* W0 = (const float*)d_in[4];
    const float* b0 = (const float*)d_in[5];
    const float* W1 = (const float*)d_in[6];
    const float* b1 = (const float*)d_in[7];
    const float* W2 = (const float*)d_in[8];
    const float* b2 = (const float*)d_in[9];
    const float* bn_gamma = (const float*)d_in[10];
    const float* bn_beta  = (const float*)d_in[11];
    const float* bn_mean  = (const float*)d_in[12];
    const float* bn_var   = (const float*)d_in[13];
    const float* pw1 = (const float*)d_in[14]; const float* pb1 = (const float*)d_in[15];
    const float* pw2 = (const float*)d_in[16]; const float* pb2 = (const float*)d_in[17];
    const float* cw1 = (const float*)d_in[18]; const float* cb1 = (const float*)d_in[19];
    const float* cw2 = (const float*)d_in[20]; const float* cb2 = (const float*)d_in[21];
    float* out = (float*)d_out;

    // Workspace layout (4-byte units):
    float* ws   = (float*)d_ws;
    float* dinv = ws;                                   // NN
    int*   cnt  = (int*)(ws + NN);                      // NN (hist, then cursor)
    int*   rs   = cnt + NN;                             // NN+1
    int*   tsum = rs + NN + 1;                          // 128
    int*   esrc = tsum + 128;                           // NE
    float* ewt  = (float*)(esrc + NE);                  // NE
    float* xa   = ewt + NE;                             // NN*8
    unsigned short* w1hi = (unsigned short*)(xa + (size_t)NN * 8);  // 16384 each
    unsigned short* w1lo = w1hi + HID * HID;
    unsigned short* w2hi = w1lo + HID * HID;
    unsigned short* w2lo = w2hi + HID * HID;
    size_t head = (size_t)NN * 2 + (NN + 1) + 128 + (size_t)NE * 2 + (size_t)NN * 8
                + (4 * HID * HID) / 2;                  // 4 ushort arrays = 2*HID*HID floats
    head = (head + 3) & ~(size_t)3;                     // 16B align
    // R1 region: NN*HID floats. Aliased: during layers 1/2 it holds bf16 hi/lo
    // planes (Ahi | Alo, each NN*HID ushort); final gather writes fp32 Cf here.
    float* R1   = ws + head;
    unsigned short* Ahi = (unsigned short*)R1;          // NN*HID ushort
    unsigned short* Alo = Ahi + (size_t)NN * HID;       // NN*HID ushort
    float* Cf   = R1;                                   // NN*HID float (same bytes)
    float* B    = R1 + (size_t)NN * HID;                // NN*HID float
    float* lig  = B + (size_t)NN * HID;                 // NG*HID
    float* pv   = lig + (size_t)NG * HID;               // 64

    const int* srcp = eidx;
    const int* dstp = eidx + NE;

    // ---- build CSR (by dst) + dinv + edge weights; split W1/W2 ----
    hipMemsetAsync(cnt, 0, NN * sizeof(int), stream);
    hist_kernel<<<(NE + 255) / 256, 256, 0, stream>>>(dstp, cnt);
    dinv_kernel<<<(NN + 255) / 256, 256, 0, stream>>>(cnt, dinv);
    scan_a<<<NTILES, 256, 0, stream>>>(cnt, rs, tsum);
    scan_b<<<1, 128, 0, stream>>>(tsum);
    scan_c<<<NTILES, 256, 0, stream>>>(rs, tsum, cnt);  // cnt becomes cursor
    bucket_kernel<<<(NE + 255) / 256, 256, 0, stream>>>(srcp, dstp, dinv, cnt, esrc, ewt);
    wconv_kernel<<<(HID * HID + 255) / 256, 256, 0, stream>>>(W1, W2, w1hi, w1lo, w2hi, w2lo);

    // ---- layer 0: aggregate x, then transform -> bf16 hi/lo planes ----
    xagg_kernel<<<(NN * 8 + 255) / 256, 256, 0, stream>>>(x, rs, esrc, ewt, dinv, xa);
    l0_transform<<<2048, 256, 0, stream>>>(xa, W0, b0,
                                           bn_gamma + 0 * HID, bn_beta + 0 * HID,
                                           bn_mean + 0 * HID, bn_var + 0 * HID, Ahi, Alo);

    const int MM_BLOCKS = NN / 32;  // 3125 (NN % 32 == 0)

    // ---- layer 1 ----
    mm_mfma<<<MM_BLOCKS, 256, 0, stream>>>(Ahi, Alo, w1hi, w1lo, B);
    gather_bn_t<true><<<(NN * 32 + 255) / 256, 256, 0, stream>>>(
        B, rs, esrc, ewt, dinv, b1,
        bn_gamma + 1 * HID, bn_beta + 1 * HID, bn_mean + 1 * HID, bn_var + 1 * HID,
        nullptr, Ahi, Alo);
    // ---- layer 2 ----
    mm_mfma<<<MM_BLOCKS, 256, 0, stream>>>(Ahi, Alo, w2hi, w2lo, B);
    gather_bn_t<false><<<(NN * 32 + 255) / 256, 256, 0, stream>>>(
        B, rs, esrc, ewt, dinv, b2,
        bn_gamma + 2 * HID, bn_beta + 2 * HID, bn_mean + 2 * HID, bn_var + 2 * HID,
        Cf, nullptr, nullptr);

    // pool -> lig
    pool_kernel<<<NG, 1024, 0, stream>>>(Cf, batch, lig);
    // pocket MLP
    pocket_kernel<<<1, 64, 0, stream>>>(pocket, pw1, pb1, pw2, pb2, pv);
    // classifier
    cls_kernel<<<NG, 96, 0, stream>>>(lig, pv, cw1, cb1, cw2, cb2, out);
}

// Round 9
// 445.488 us; speedup vs baseline: 1.0651x; 1.0225x over previous
//
#include <hip/hip_runtime.h>

// Problem constants (match reference setup_inputs)
#define NN 100000
#define NE 600000
#define NG 256
#define HID 128
#define BN_EPS 1e-5f

#define SCAN_TILE 1024
#define NTILES ((NN + SCAN_TILE - 1) / SCAN_TILE)  // 98

typedef __attribute__((ext_vector_type(8))) short short8;
typedef __attribute__((ext_vector_type(4))) float float4v;

// bf16 round-to-nearest-even helpers
__device__ __forceinline__ unsigned short f2bf_rn(float f) {
    unsigned u = __float_as_uint(f);
    unsigned r = u + 0x7FFFu + ((u >> 16) & 1u);
    return (unsigned short)(r >> 16);
}
__device__ __forceinline__ float bf2f(unsigned short h) {
    return __uint_as_float((unsigned)h << 16);
}

// ---------------- histogram of dst (in-degree) ----------------

__global__ __launch_bounds__(256) void hist_kernel(const int* __restrict__ dst, int* __restrict__ cnt) {
    int e = blockIdx.x * blockDim.x + threadIdx.x;
    if (e < NE) atomicAdd(&cnt[dst[e]], 1);
}

// ---------------- 2-level exclusive scan of cnt -> row_start (+ dinv fused) ----------------

__global__ __launch_bounds__(256) void scan_a(const int* __restrict__ cnt, int* __restrict__ rs,
                                              int* __restrict__ tsum, float* __restrict__ dinv) {
    __shared__ int s[256];
    int t = threadIdx.x;
    int base = blockIdx.x * SCAN_TILE;
    int idx = base + t * 4;
    int v0 = (idx + 0 < NN) ? cnt[idx + 0] : 0;
    int v1 = (idx + 1 < NN) ? cnt[idx + 1] : 0;
    int v2 = (idx + 2 < NN) ? cnt[idx + 2] : 0;
    int v3 = (idx + 3 < NN) ? cnt[idx + 3] : 0;
    if (idx + 0 < NN) dinv[idx + 0] = rsqrtf((float)v0 + 1.0f);
    if (idx + 1 < NN) dinv[idx + 1] = rsqrtf((float)v1 + 1.0f);
    if (idx + 2 < NN) dinv[idx + 2] = rsqrtf((float)v2 + 1.0f);
    if (idx + 3 < NN) dinv[idx + 3] = rsqrtf((float)v3 + 1.0f);
    int local = v0 + v1 + v2 + v3;
    s[t] = local;
    __syncthreads();
    for (int off = 1; off < 256; off <<= 1) {
        int x = (t >= off) ? s[t - off] : 0;
        __syncthreads();
        s[t] += x;
        __syncthreads();
    }
    int pre = s[t] - local;  // exclusive prefix within tile
    if (t == 255) tsum[blockIdx.x] = s[255];
    if (idx + 0 < NN) rs[idx + 0] = pre; pre += v0;
    if (idx + 1 < NN) rs[idx + 1] = pre; pre += v1;
    if (idx + 2 < NN) rs[idx + 2] = pre; pre += v2;
    if (idx + 3 < NN) rs[idx + 3] = pre;
}

__global__ __launch_bounds__(128) void scan_b(int* __restrict__ tsum) {
    __shared__ int s[128];
    int t = threadIdx.x;
    int v = (t < NTILES) ? tsum[t] : 0;
    s[t] = v;
    __syncthreads();
    for (int off = 1; off < 128; off <<= 1) {
        int x = (t >= off) ? s[t - off] : 0;
        __syncthreads();
        s[t] += x;
        __syncthreads();
    }
    if (t < NTILES) tsum[t] = s[t] - v;  // exclusive
}

__global__ __launch_bounds__(256) void scan_c(int* __restrict__ rs, const int* __restrict__ tsum,
                                              int* __restrict__ cursor) {
    int t = threadIdx.x;
    int base = blockIdx.x * SCAN_TILE;
    int off = tsum[blockIdx.x];
    for (int k = 0; k < 4; k++) {
        int idx = base + t * 4 + k;
        if (idx < NN) {
            int v = rs[idx] + off;
            rs[idx] = v;
            cursor[idx] = v;
        }
    }
    if (blockIdx.x == 0 && t == 0) rs[NN] = NE;
}

// ---------------- bucket edges by dst (also precompute edge weights) ----------------

__global__ __launch_bounds__(256) void bucket_kernel(const int* __restrict__ src, const int* __restrict__ dst,
                                                     const float* __restrict__ dinv,
                                                     int* __restrict__ cursor,
                                                     int* __restrict__ esrc, float* __restrict__ ewt) {
    int e = blockIdx.x * blockDim.x + threadIdx.x;
    if (e < NE) {
        int s = src[e], d = dst[e];
        int pos = atomicAdd(&cursor[d], 1);
        esrc[pos] = s;
        ewt[pos] = dinv[s] * dinv[d];
    }
}

// ---------------- prep: split W1/W2 (transposed) + pocket MLP ----------------
// blocks 0..63: wconv over 16384 elems; block 64: pocket 28->64->64.

__global__ __launch_bounds__(256) void prep_kernel(const float* __restrict__ W1, const float* __restrict__ W2,
                                                   unsigned short* __restrict__ w1hi, unsigned short* __restrict__ w1lo,
                                                   unsigned short* __restrict__ w2hi, unsigned short* __restrict__ w2lo,
                                                   const float* __restrict__ pocket,
                                                   const float* __restrict__ pw1, const float* __restrict__ pb1,
                                                   const float* __restrict__ pw2, const float* __restrict__ pb2,
                                                   float* __restrict__ pv) {
    if (blockIdx.x < 64) {
        int t = blockIdx.x * 256 + threadIdx.x;
        int k = t >> 7, n = t & 127;      // W[k][n]
        int to = n * HID + k;             // Wt[n][k]
        float v1 = W1[t];
        unsigned short h1 = f2bf_rn(v1);
        w1hi[to] = h1;
        w1lo[to] = f2bf_rn(v1 - bf2f(h1));
        float v2 = W2[t];
        unsigned short h2 = f2bf_rn(v2);
        w2hi[to] = h2;
        w2lo[to] = f2bf_rn(v2 - bf2f(h2));
    } else {
        __shared__ float t1[64];
        int j = threadIdx.x;
        if (j < 64) {
            float acc = pb1[j];
            for (int k = 0; k < 28; k++) acc = fmaf(pocket[k], pw1[k * 64 + j], acc);
            t1[j] = fmaxf(acc, 0.f);
        }
        __syncthreads();
        if (j < 64) {
            float acc2 = pb2[j];
            for (int k = 0; k < 64; k++) acc2 = fmaf(t1[k], pw2[k * 64 + j], acc2);
            pv[j] = acc2;
        }
    }
}

// ---------------- layer 0 part A: aggregate raw x (7-dim) -> xa [NN,8] ----------------

__global__ __launch_bounds__(256) void xagg_kernel(const float* __restrict__ x,
                                                   const int* __restrict__ rs,
                                                   const int* __restrict__ esrc,
                                                   const float* __restrict__ ewt,
                                                   const float* __restrict__ dinv,
                                                   float* __restrict__ xa) {
    int t = blockIdx.x * blockDim.x + threadIdx.x;
    int f = t & 7;
    int n = t >> 3;
    if (n >= NN) return;
    float acc = 0.f;
    if (f < 7) {
        float di = dinv[n];
        acc = x[n * 7 + f] * di * di;
        int e0 = rs[n], e1 = rs[n + 1];
        int e = e0;
        for (; e + 1 < e1; e += 2) {
            int s0 = esrc[e], s1 = esrc[e + 1];
            float w0 = ewt[e], w1 = ewt[e + 1];
            float a0 = x[s0 * 7 + f];
            float a1 = x[s1 * 7 + f];
            acc = fmaf(a0, w0, acc);
            acc = fmaf(a1, w1, acc);
        }
        if (e < e1) acc = fmaf(x[esrc[e] * 7 + f], ewt[e], acc);
    }
    xa[n * 8 + f] = acc;
}

// ---------------- layer 0 part B: xa @ W0 + b -> BN -> ReLU -> bf16 hi/lo ----------------
// v2: thread owns 4 consecutive features (ushort4 stores); 8 nodes per iter.

__global__ __launch_bounds__(256) void l0_transform(const float* __restrict__ xa,
                                                    const float* __restrict__ W,
                                                    const float* __restrict__ b,
                                                    const float* __restrict__ gamma,
                                                    const float* __restrict__ beta,
                                                    const float* __restrict__ mean,
                                                    const float* __restrict__ var,
                                                    unsigned short* __restrict__ ohi,
                                                    unsigned short* __restrict__ olo) {
    int c4 = threadIdx.x & 31;   // feature group: j = c4*4 + i
    int r  = threadIdx.x >> 5;   // node within 8-group
    float w[7][4];
#pragma unroll
    for (int k = 0; k < 7; k++)
#pragma unroll
        for (int i = 0; i < 4; i++) w[k][i] = W[k * HID + c4 * 4 + i];
    float4 bb = ((const float4*)b)[c4];
    float4 ga = ((const float4*)gamma)[c4];
    float4 be = ((const float4*)beta)[c4];
    float4 me = ((const float4*)mean)[c4];
    float4 va = ((const float4*)var)[c4];
    float4 sc;
    sc.x = ga.x * rsqrtf(va.x + BN_EPS);
    sc.y = ga.y * rsqrtf(va.y + BN_EPS);
    sc.z = ga.z * rsqrtf(va.z + BN_EPS);
    sc.w = ga.w * rsqrtf(va.w + BN_EPS);
    __shared__ float s[8][8];
    for (int n0 = blockIdx.x * 8; n0 < NN; n0 += gridDim.x * 8) {
        __syncthreads();
        if (threadIdx.x < 64) s[threadIdx.x >> 3][threadIdx.x & 7] = xa[n0 * 8 + threadIdx.x];
        __syncthreads();
        float o0 = bb.x, o1 = bb.y, o2 = bb.z, o3 = bb.w;
#pragma unroll
        for (int k = 0; k < 7; k++) {
            float xv = s[r][k];
            o0 = fmaf(xv, w[k][0], o0);
            o1 = fmaf(xv, w[k][1], o1);
            o2 = fmaf(xv, w[k][2], o2);
            o3 = fmaf(xv, w[k][3], o3);
        }
        float v0 = fmaxf(fmaf(o0 - me.x, sc.x, be.x), 0.f);
        float v1 = fmaxf(fmaf(o1 - me.y, sc.y, be.y), 0.f);
        float v2 = fmaxf(fmaf(o2 - me.z, sc.z, be.z), 0.f);
        float v3 = fmaxf(fmaf(o3 - me.w, sc.w, be.w), 0.f);
        ushort4 hi4, lo4;
        hi4.x = f2bf_rn(v0); lo4.x = f2bf_rn(v0 - bf2f(hi4.x));
        hi4.y = f2bf_rn(v1); lo4.y = f2bf_rn(v1 - bf2f(hi4.y));
        hi4.z = f2bf_rn(v2); lo4.z = f2bf_rn(v2 - bf2f(hi4.z));
        hi4.w = f2bf_rn(v3); lo4.w = f2bf_rn(v3 - bf2f(hi4.w));
        size_t base = (size_t)(n0 + r) * HID + c4 * 4;
        *(ushort4*)(ohi + base) = hi4;
        *(ushort4*)(olo + base) = lo4;
    }
}

// ---------------- layers 1/2 matmul via MFMA (split-bf16 fp32-accurate) ----------------

__global__ __launch_bounds__(256) void mm_mfma(const unsigned short* __restrict__ Ahi,
                                               const unsigned short* __restrict__ Alo,
                                               const unsigned short* __restrict__ Whi,
                                               const unsigned short* __restrict__ Wlo,
                                               float* __restrict__ out) {
    int wave = threadIdx.x >> 6;
    int lane = threadIdx.x & 63;
    int mrow = lane & 15;
    int quad = lane >> 4;
    int m0 = blockIdx.x * 32;
    int n0 = wave * 32;

    short8 bh[2][4], bl[2][4];
#pragma unroll
    for (int ct = 0; ct < 2; ct++) {
#pragma unroll
        for (int kc = 0; kc < 4; kc++) {
            size_t off = (size_t)(n0 + ct * 16 + mrow) * HID + kc * 32 + quad * 8;
            bh[ct][kc] = *(const short8*)(Whi + off);
            bl[ct][kc] = *(const short8*)(Wlo + off);
        }
    }

    float4v acc[2][2];
#pragma unroll
    for (int rt = 0; rt < 2; rt++)
#pragma unroll
        for (int ct = 0; ct < 2; ct++) {
            acc[rt][ct].x = 0.f; acc[rt][ct].y = 0.f;
            acc[rt][ct].z = 0.f; acc[rt][ct].w = 0.f;
        }

#pragma unroll
    for (int kc = 0; kc < 4; kc++) {
#pragma unroll
        for (int rt = 0; rt < 2; rt++) {
            size_t aoff = (size_t)(m0 + rt * 16 + mrow) * HID + kc * 32 + quad * 8;
            short8 ah = *(const short8*)(Ahi + aoff);
            short8 al = *(const short8*)(Alo + aoff);
#pragma unroll
            for (int ct = 0; ct < 2; ct++) {
                acc[rt][ct] = __builtin_amdgcn_mfma_f32_16x16x32_bf16(ah, bh[ct][kc], acc[rt][ct], 0, 0, 0);
                acc[rt][ct] = __builtin_amdgcn_mfma_f32_16x16x32_bf16(ah, bl[ct][kc], acc[rt][ct], 0, 0, 0);
                acc[rt][ct] = __builtin_amdgcn_mfma_f32_16x16x32_bf16(al, bh[ct][kc], acc[rt][ct], 0, 0, 0);
                acc[rt][ct] = __builtin_amdgcn_mfma_f32_16x16x32_bf16(al, bl[ct][kc], acc[rt][ct], 0, 0, 0);
            }
        }
    }

#pragma unroll
    for (int rt = 0; rt < 2; rt++) {
#pragma unroll
        for (int ct = 0; ct < 2; ct++) {
            int col = n0 + ct * 16 + mrow;
#pragma unroll
            for (int r = 0; r < 4; r++) {
                int row = m0 + rt * 16 + quad * 4 + r;
                out[(size_t)row * HID + col] = acc[rt][ct][r];
            }
        }
    }
}

// ---------------- gather-aggregate + self-loop + bias + BN + ReLU ----------------
// BF16OUT: write planar bf16 hi/lo (feeds next mm_mfma); else fp32 (feeds pool).

template <bool BF16OUT>
__global__ __launch_bounds__(256) void gather_bn_t(const float* __restrict__ hl,
                                                   const int* __restrict__ rs,
                                                   const int* __restrict__ esrc,
                                                   const float* __restrict__ ewt,
                                                   const float* __restrict__ dinv,
                                                   const float* __restrict__ b,
                                                   const float* __restrict__ gamma,
                                                   const float* __restrict__ beta,
                                                   const float* __restrict__ mean,
                                                   const float* __restrict__ var,
                                                   float* __restrict__ outf,
                                                   unsigned short* __restrict__ ohi,
                                                   unsigned short* __restrict__ olo) {
    int t = blockIdx.x * blockDim.x + threadIdx.x;
    int lane = t & 31;
    int n = t >> 5;
    if (n >= NN) return;
    const float4* hl4 = (const float4*)hl;
    float di = dinv[n];
    float4 self = hl4[(size_t)n * 32 + lane];
    float4 bb = ((const float4*)b)[lane];
    float dsq = di * di;
    float4 acc;
    acc.x = fmaf(self.x, dsq, bb.x);
    acc.y = fmaf(self.y, dsq, bb.y);
    acc.z = fmaf(self.z, dsq, bb.z);
    acc.w = fmaf(self.w, dsq, bb.w);
    int e0 = rs[n], e1 = rs[n + 1];
    int e = e0;
    for (; e + 1 < e1; e += 2) {
        int s0 = esrc[e], s1 = esrc[e + 1];
        float w0 = ewt[e], w1 = ewt[e + 1];
        float4 v0 = hl4[(size_t)s0 * 32 + lane];
        float4 v1 = hl4[(size_t)s1 * 32 + lane];
        acc.x = fmaf(v0.x, w0, acc.x); acc.y = fmaf(v0.y, w0, acc.y);
        acc.z = fmaf(v0.z, w0, acc.z); acc.w = fmaf(v0.w, w0, acc.w);
        acc.x = fmaf(v1.x, w1, acc.x); acc.y = fmaf(v1.y, w1, acc.y);
        acc.z = fmaf(v1.z, w1, acc.z); acc.w = fmaf(v1.w, w1, acc.w);
    }
    if (e < e1) {
        int s0 = esrc[e];
        float w0 = ewt[e];
        float4 v0 = hl4[(size_t)s0 * 32 + lane];
        acc.x = fmaf(v0.x, w0, acc.x); acc.y = fmaf(v0.y, w0, acc.y);
        acc.z = fmaf(v0.z, w0, acc.z); acc.w = fmaf(v0.w, w0, acc.w);
    }
    float4 ga = ((const float4*)gamma)[lane];
    float4 be = ((const float4*)beta)[lane];
    float4 me = ((const float4*)mean)[lane];
    float4 va = ((const float4*)var)[lane];
    float4 o;
    o.x = fmaxf(fmaf(acc.x - me.x, ga.x * rsqrtf(va.x + BN_EPS), be.x), 0.f);
    o.y = fmaxf(fmaf(acc.y - me.y, ga.y * rsqrtf(va.y + BN_EPS), be.y), 0.f);
    o.z = fmaxf(fmaf(acc.z - me.z, ga.z * rsqrtf(va.z + BN_EPS), be.z), 0.f);
    o.w = fmaxf(fmaf(acc.w - me.w, ga.w * rsqrtf(va.w + BN_EPS), be.w), 0.f);
    if (BF16OUT) {
        ushort4 hi4, lo4;
        hi4.x = f2bf_rn(o.x); lo4.x = f2bf_rn(o.x - bf2f(hi4.x));
        hi4.y = f2bf_rn(o.y); lo4.y = f2bf_rn(o.y - bf2f(hi4.y));
        hi4.z = f2bf_rn(o.z); lo4.z = f2bf_rn(o.z - bf2f(hi4.z));
        hi4.w = f2bf_rn(o.w); lo4.w = f2bf_rn(o.w - bf2f(hi4.w));
        ((ushort4*)ohi)[(size_t)n * 32 + lane] = hi4;
        ((ushort4*)olo)[(size_t)n * 32 + lane] = lo4;
    } else {
        ((float4*)outf)[(size_t)n * 32 + lane] = o;
    }
}

// ---------------- fused global mean pool + classifier ----------------
// Block g: mean over graph g's nodes -> LDS emb[0..127]; emb[128..191]=pv;
// hidden 96 = relu(emb@cw1+cb1); out[g] = hidden@cw2 + cb2.

__global__ __launch_bounds__(1024) void poolcls_kernel(const float* __restrict__ h,
                                                       const int* __restrict__ batch,
                                                       const float* __restrict__ pv,
                                                       const float* __restrict__ cw1,
                                                       const float* __restrict__ cb1,
                                                       const float* __restrict__ cw2,
                                                       const float* __restrict__ cb2,
                                                       float* __restrict__ out) {
    int g = blockIdx.x;
    int lane = threadIdx.x & 31;   // float4 index within feature row
    int row = threadIdx.x >> 5;    // 0..31
    __shared__ int se[2];
    __shared__ float emb[192];
    __shared__ float hid[96];
    if (threadIdx.x < 2) {
        int target = g + threadIdx.x;
        int lo = 0, hi = NN;
        while (lo < hi) {
            int mid = (lo + hi) >> 1;
            if (batch[mid] < target) lo = mid + 1; else hi = mid;
        }
        se[threadIdx.x] = lo;
    }
    if (threadIdx.x < 64) emb[128 + threadIdx.x] = pv[threadIdx.x];
    __syncthreads();
    int start = se[0], end = se[1];
    const float4* h4 = (const float4*)h;
    float4 acc = make_float4(0.f, 0.f, 0.f, 0.f);
    for (int n = start + row; n < end; n += 32) {
        float4 v = h4[(size_t)n * 32 + lane];
        acc.x += v.x; acc.y += v.y; acc.z += v.z; acc.w += v.w;
    }
    __shared__ float4 part[32][32];
    part[row][lane] = acc;
    __syncthreads();
#pragma unroll
    for (int off = 16; off >= 1; off >>= 1) {
        if (row < off) {
            float4 a = part[row][lane];
            float4 c = part[row + off][lane];
            a.x += c.x; a.y += c.y; a.z += c.z; a.w += c.w;
            part[row][lane] = a;
        }
        __syncthreads();
    }
    if (row == 0) {
        float inv = 1.0f / fmaxf((float)(end - start), 1.0f);
        float4 a = part[0][lane];
        a.x *= inv; a.y *= inv; a.z *= inv; a.w *= inv;
        ((float4*)emb)[lane] = a;
    }
    __syncthreads();
    int j = threadIdx.x;
    if (j < 96) {
        float a = cb1[j];
        for (int k = 0; k < 192; k++) a = fmaf(emb[k], cw1[k * 96 + j], a);
        hid[j] = fmaxf(a, 0.f) * cw2[j];
    }
    __syncthreads();
    if (j == 0) {
        float s = cb2[0];
        for (int k = 0; k < 96; k++) s += hid[k];
        out[g] = s;
    }
}

extern "C" void kernel_launch(void* const* d_in, const int* in_sizes, int n_in,
                              void* d_out, int out_size, void* d_ws, size_t ws_size,
                              hipStream_t stream) {
    const float* x        = (const float*)d_in[0];
    const int*   eidx     = (const int*)d_in[1];
    const int*   batch    = (const int*)d_in[2];
    const float* pocket   = (const float*)d_in[3];
    const float* W0 = (const float*)d_in[4];
    const float* b0 = (const float*)d_in[5];
    const float* W1 = (const float*)d_in[6];
    const float* b1 = (const float*)d_in[7];
    const float* W2 = (const float*)d_in[8];
    const float* b2 = (const float*)d_in[9];
    const float* bn_gamma = (const float*)d_in[10];
    const float* bn_beta  = (const float*)d_in[11];
    const float* bn_mean  = (const float*)d_in[12];
    const float* bn_var   = (const float*)d_in[13];
    const float* pw1 = (const float*)d_in[14]; const float* pb1 = (const float*)d_in[15];
    const float* pw2 = (const float*)d_in[16]; const float* pb2 = (const float*)d_in[17];
    const float* cw1 = (const float*)d_in[18]; const float* cb1 = (const float*)d_in[19];
    const float* cw2 = (const float*)d_in[20]; const float* cb2 = (const float*)d_in[21];
    float* out = (float*)d_out;

    // Workspace layout (4-byte units):
    float* ws   = (float*)d_ws;
    float* dinv = ws;                                   // NN
    int*   cnt  = (int*)(ws + NN);                      // NN (hist, then cursor)
    int*   rs   = cnt + NN;                             // NN+1
    int*   tsum = rs + NN + 1;                          // 128
    int*   esrc = tsum + 128;                           // NE
    float* ewt  = (float*)(esrc + NE);                  // NE
    float* xa   = ewt + NE;                             // NN*8
    unsigned short* w1hi = (unsigned short*)(xa + (size_t)NN * 8);  // 16384 each
    unsigned short* w1lo = w1hi + HID * HID;
    unsigned short* w2hi = w1lo + HID * HID;
    unsigned short* w2lo = w2hi + HID * HID;
    size_t head = (size_t)NN * 2 + (NN + 1) + 128 + (size_t)NE * 2 + (size_t)NN * 8
                + (4 * HID * HID) / 2;                  // 4 ushort arrays = 2*HID*HID floats
    head = (head + 3) & ~(size_t)3;                     // 16B align
    // R1 region: NN*HID floats. Aliased: during layers 1/2 it holds bf16 hi/lo
    // planes (Ahi | Alo); final gather writes fp32 Cf here.
    float* R1   = ws + head;
    unsigned short* Ahi = (unsigned short*)R1;          // NN*HID ushort
    unsigned short* Alo = Ahi + (size_t)NN * HID;       // NN*HID ushort
    float* Cf   = R1;                                   // NN*HID float (same bytes)
    float* B    = R1 + (size_t)NN * HID;                // NN*HID float
    float* pv   = B + (size_t)NN * HID;                 // 64

    const int* srcp = eidx;
    const int* dstp = eidx + NE;

    // ---- build CSR (by dst) + dinv + edge weights; split W1/W2 + pocket ----
    hipMemsetAsync(cnt, 0, NN * sizeof(int), stream);
    hist_kernel<<<(NE + 255) / 256, 256, 0, stream>>>(dstp, cnt);
    scan_a<<<NTILES, 256, 0, stream>>>(cnt, rs, tsum, dinv);
    scan_b<<<1, 128, 0, stream>>>(tsum);
    scan_c<<<NTILES, 256, 0, stream>>>(rs, tsum, cnt);  // cnt becomes cursor
    bucket_kernel<<<(NE + 255) / 256, 256, 0, stream>>>(srcp, dstp, dinv, cnt, esrc, ewt);
    prep_kernel<<<65, 256, 0, stream>>>(W1, W2, w1hi, w1lo, w2hi, w2lo,
                                        pocket, pw1, pb1, pw2, pb2, pv);

    // ---- layer 0: aggregate x, then transform -> bf16 hi/lo planes ----
    xagg_kernel<<<(NN * 8 + 255) / 256, 256, 0, stream>>>(x, rs, esrc, ewt, dinv, xa);
    l0_transform<<<2048, 256, 0, stream>>>(xa, W0, b0,
                                           bn_gamma + 0 * HID, bn_beta + 0 * HID,
                                           bn_mean + 0 * HID, bn_var + 0 * HID, Ahi, Alo);

    const int MM_BLOCKS = NN / 32;  // 3125 (NN % 32 == 0)

    // ---- layer 1 ----
    mm_mfma<<<MM_BLOCKS, 256, 0, stream>>>(Ahi, Alo, w1hi, w1lo, B);
    gather_bn_t<true><<<(NN * 32 + 255) / 256, 256, 0, stream>>>(
        B, rs, esrc, ewt, dinv, b1,
        bn_gamma + 1 * HID, bn_beta + 1 * HID, bn_mean + 1 * HID, bn_var + 1 * HID,
        nullptr, Ahi, Alo);
    // ---- layer 2 ----
    mm_mfma<<<MM_BLOCKS, 256, 0, stream>>>(Ahi, Alo, w2hi, w2lo, B);
    gather_bn_t<false><<<(NN * 32 + 255) / 256, 256, 0, stream>>>(
        B, rs, esrc, ewt, dinv, b2,
        bn_gamma + 2 * HID, bn_beta + 2 * HID, bn_mean + 2 * HID, bn_var + 2 * HID,
        Cf, nullptr, nullptr);

    // fused pool + classifier
    poolcls_kernel<<<NG, 1024, 0, stream>>>(Cf, batch, pv, cw1, cb1, cw2, cb2, out);
}

// Round 10
// 403.469 us; speedup vs baseline: 1.1760x; 1.1041x over previous
//
#include <hip/hip_runtime.h>

// Problem constants (match reference setup_inputs)
#define NN 100000
#define NE 600000
#define NG 256
#define HID 128
#define BN_EPS 1e-5f

#define SCAN_TILE 1024
#define NTILES ((NN + SCAN_TILE - 1) / SCAN_TILE)  // 98

typedef __attribute__((ext_vector_type(8))) short short8;
typedef __attribute__((ext_vector_type(4))) float float4v;

// bf16 round-to-nearest-even helpers
__device__ __forceinline__ unsigned short f2bf_rn(float f) {
    unsigned u = __float_as_uint(f);
    unsigned r = u + 0x7FFFu + ((u >> 16) & 1u);
    return (unsigned short)(r >> 16);
}
__device__ __forceinline__ float bf2f(unsigned short h) {
    return __uint_as_float((unsigned)h << 16);
}
__device__ __forceinline__ float4 us4tof4(ushort4 u) {
    return make_float4(bf2f(u.x), bf2f(u.y), bf2f(u.z), bf2f(u.w));
}

// ---------------- histogram of dst (in-degree) ----------------

__global__ __launch_bounds__(256) void hist_kernel(const int* __restrict__ dst, int* __restrict__ cnt) {
    int e = blockIdx.x * blockDim.x + threadIdx.x;
    if (e < NE) atomicAdd(&cnt[dst[e]], 1);
}

// ---------------- 2-level exclusive scan of cnt -> row_start (+ dinv fused) ----------------

__global__ __launch_bounds__(256) void scan_a(const int* __restrict__ cnt, int* __restrict__ rs,
                                              int* __restrict__ tsum, float* __restrict__ dinv) {
    __shared__ int s[256];
    int t = threadIdx.x;
    int base = blockIdx.x * SCAN_TILE;
    int idx = base + t * 4;
    int v0 = (idx + 0 < NN) ? cnt[idx + 0] : 0;
    int v1 = (idx + 1 < NN) ? cnt[idx + 1] : 0;
    int v2 = (idx + 2 < NN) ? cnt[idx + 2] : 0;
    int v3 = (idx + 3 < NN) ? cnt[idx + 3] : 0;
    if (idx + 0 < NN) dinv[idx + 0] = rsqrtf((float)v0 + 1.0f);
    if (idx + 1 < NN) dinv[idx + 1] = rsqrtf((float)v1 + 1.0f);
    if (idx + 2 < NN) dinv[idx + 2] = rsqrtf((float)v2 + 1.0f);
    if (idx + 3 < NN) dinv[idx + 3] = rsqrtf((float)v3 + 1.0f);
    int local = v0 + v1 + v2 + v3;
    s[t] = local;
    __syncthreads();
    for (int off = 1; off < 256; off <<= 1) {
        int x = (t >= off) ? s[t - off] : 0;
        __syncthreads();
        s[t] += x;
        __syncthreads();
    }
    int pre = s[t] - local;  // exclusive prefix within tile
    if (t == 255) tsum[blockIdx.x] = s[255];
    if (idx + 0 < NN) rs[idx + 0] = pre; pre += v0;
    if (idx + 1 < NN) rs[idx + 1] = pre; pre += v1;
    if (idx + 2 < NN) rs[idx + 2] = pre; pre += v2;
    if (idx + 3 < NN) rs[idx + 3] = pre;
}

__global__ __launch_bounds__(128) void scan_b(int* __restrict__ tsum) {
    __shared__ int s[128];
    int t = threadIdx.x;
    int v = (t < NTILES) ? tsum[t] : 0;
    s[t] = v;
    __syncthreads();
    for (int off = 1; off < 128; off <<= 1) {
        int x = (t >= off) ? s[t - off] : 0;
        __syncthreads();
        s[t] += x;
        __syncthreads();
    }
    if (t < NTILES) tsum[t] = s[t] - v;  // exclusive
}

__global__ __launch_bounds__(256) void scan_c(int* __restrict__ rs, const int* __restrict__ tsum,
                                              int* __restrict__ cursor) {
    int t = threadIdx.x;
    int base = blockIdx.x * SCAN_TILE;
    int off = tsum[blockIdx.x];
    for (int k = 0; k < 4; k++) {
        int idx = base + t * 4 + k;
        if (idx < NN) {
            int v = rs[idx] + off;
            rs[idx] = v;
            cursor[idx] = v;
        }
    }
    if (blockIdx.x == 0 && t == 0) rs[NN] = NE;
}

// ---------------- bucket edges by dst (also precompute edge weights) ----------------

__global__ __launch_bounds__(256) void bucket_kernel(const int* __restrict__ src, const int* __restrict__ dst,
                                                     const float* __restrict__ dinv,
                                                     int* __restrict__ cursor,
                                                     int* __restrict__ esrc, float* __restrict__ ewt) {
    int e = blockIdx.x * blockDim.x + threadIdx.x;
    if (e < NE) {
        int s = src[e], d = dst[e];
        int pos = atomicAdd(&cursor[d], 1);
        esrc[pos] = s;
        ewt[pos] = dinv[s] * dinv[d];
    }
}

// ---------------- prep: split W1/W2 (transposed) + pocket MLP ----------------

__global__ __launch_bounds__(256) void prep_kernel(const float* __restrict__ W1, const float* __restrict__ W2,
                                                   unsigned short* __restrict__ w1hi, unsigned short* __restrict__ w1lo,
                                                   unsigned short* __restrict__ w2hi, unsigned short* __restrict__ w2lo,
                                                   const float* __restrict__ pocket,
                                                   const float* __restrict__ pw1, const float* __restrict__ pb1,
                                                   const float* __restrict__ pw2, const float* __restrict__ pb2,
                                                   float* __restrict__ pv) {
    if (blockIdx.x < 64) {
        int t = blockIdx.x * 256 + threadIdx.x;
        int k = t >> 7, n = t & 127;      // W[k][n]
        int to = n * HID + k;             // Wt[n][k]
        float v1 = W1[t];
        unsigned short h1 = f2bf_rn(v1);
        w1hi[to] = h1;
        w1lo[to] = f2bf_rn(v1 - bf2f(h1));
        float v2 = W2[t];
        unsigned short h2 = f2bf_rn(v2);
        w2hi[to] = h2;
        w2lo[to] = f2bf_rn(v2 - bf2f(h2));
    } else {
        __shared__ float t1[64];
        int j = threadIdx.x;
        if (j < 64) {
            float acc = pb1[j];
            for (int k = 0; k < 28; k++) acc = fmaf(pocket[k], pw1[k * 64 + j], acc);
            t1[j] = fmaxf(acc, 0.f);
        }
        __syncthreads();
        if (j < 64) {
            float acc2 = pb2[j];
            for (int k = 0; k < 64; k++) acc2 = fmaf(t1[k], pw2[k * 64 + j], acc2);
            pv[j] = acc2;
        }
    }
}

// ---------------- layer 0 part A: aggregate raw x (7-dim) -> xa [NN,8] ----------------

__global__ __launch_bounds__(256) void xagg_kernel(const float* __restrict__ x,
                                                   const int* __restrict__ rs,
                                                   const int* __restrict__ esrc,
                                                   const float* __restrict__ ewt,
                                                   const float* __restrict__ dinv,
                                                   float* __restrict__ xa) {
    int t = blockIdx.x * blockDim.x + threadIdx.x;
    int f = t & 7;
    int n = t >> 3;
    if (n >= NN) return;
    float acc = 0.f;
    if (f < 7) {
        float di = dinv[n];
        acc = x[n * 7 + f] * di * di;
        int e0 = rs[n], e1 = rs[n + 1];
        int e = e0;
        for (; e + 1 < e1; e += 2) {
            int s0 = esrc[e], s1 = esrc[e + 1];
            float w0 = ewt[e], w1 = ewt[e + 1];
            float a0 = x[s0 * 7 + f];
            float a1 = x[s1 * 7 + f];
            acc = fmaf(a0, w0, acc);
            acc = fmaf(a1, w1, acc);
        }
        if (e < e1) acc = fmaf(x[esrc[e] * 7 + f], ewt[e], acc);
    }
    xa[n * 8 + f] = acc;
}

// ---------------- layer 0 part B: xa @ W0 + b -> BN -> ReLU -> bf16 hi/lo ----------------

__global__ __launch_bounds__(256) void l0_transform(const float* __restrict__ xa,
                                                    const float* __restrict__ W,
                                                    const float* __restrict__ b,
                                                    const float* __restrict__ gamma,
                                                    const float* __restrict__ beta,
                                                    const float* __restrict__ mean,
                                                    const float* __restrict__ var,
                                                    unsigned short* __restrict__ ohi,
                                                    unsigned short* __restrict__ olo) {
    int c4 = threadIdx.x & 31;   // feature group: j = c4*4 + i
    int r  = threadIdx.x >> 5;   // node within 8-group
    float w[7][4];
#pragma unroll
    for (int k = 0; k < 7; k++)
#pragma unroll
        for (int i = 0; i < 4; i++) w[k][i] = W[k * HID + c4 * 4 + i];
    float4 bb = ((const float4*)b)[c4];
    float4 ga = ((const float4*)gamma)[c4];
    float4 be = ((const float4*)beta)[c4];
    float4 me = ((const float4*)mean)[c4];
    float4 va = ((const float4*)var)[c4];
    float4 sc;
    sc.x = ga.x * rsqrtf(va.x + BN_EPS);
    sc.y = ga.y * rsqrtf(va.y + BN_EPS);
    sc.z = ga.z * rsqrtf(va.z + BN_EPS);
    sc.w = ga.w * rsqrtf(va.w + BN_EPS);
    __shared__ float s[8][8];
    for (int n0 = blockIdx.x * 8; n0 < NN; n0 += gridDim.x * 8) {
        __syncthreads();
        if (threadIdx.x < 64) s[threadIdx.x >> 3][threadIdx.x & 7] = xa[n0 * 8 + threadIdx.x];
        __syncthreads();
        float o0 = bb.x, o1 = bb.y, o2 = bb.z, o3 = bb.w;
#pragma unroll
        for (int k = 0; k < 7; k++) {
            float xv = s[r][k];
            o0 = fmaf(xv, w[k][0], o0);
            o1 = fmaf(xv, w[k][1], o1);
            o2 = fmaf(xv, w[k][2], o2);
            o3 = fmaf(xv, w[k][3], o3);
        }
        float v0 = fmaxf(fmaf(o0 - me.x, sc.x, be.x), 0.f);
        float v1 = fmaxf(fmaf(o1 - me.y, sc.y, be.y), 0.f);
        float v2 = fmaxf(fmaf(o2 - me.z, sc.z, be.z), 0.f);
        float v3 = fmaxf(fmaf(o3 - me.w, sc.w, be.w), 0.f);
        ushort4 hi4, lo4;
        hi4.x = f2bf_rn(v0); lo4.x = f2bf_rn(v0 - bf2f(hi4.x));
        hi4.y = f2bf_rn(v1); lo4.y = f2bf_rn(v1 - bf2f(hi4.y));
        hi4.z = f2bf_rn(v2); lo4.z = f2bf_rn(v2 - bf2f(hi4.z));
        hi4.w = f2bf_rn(v3); lo4.w = f2bf_rn(v3 - bf2f(hi4.w));
        size_t base = (size_t)(n0 + r) * HID + c4 * 4;
        *(ushort4*)(ohi + base) = hi4;
        *(ushort4*)(olo + base) = lo4;
    }
}

// ---------------- layers 1/2 matmul via MFMA (split-bf16 fp32-accurate) ----------------
// Output now quantized to bf16 (RN) — halves the downstream gather's bytes.

__global__ __launch_bounds__(256) void mm_mfma(const unsigned short* __restrict__ Ahi,
                                               const unsigned short* __restrict__ Alo,
                                               const unsigned short* __restrict__ Whi,
                                               const unsigned short* __restrict__ Wlo,
                                               unsigned short* __restrict__ out) {
    int wave = threadIdx.x >> 6;
    int lane = threadIdx.x & 63;
    int mrow = lane & 15;
    int quad = lane >> 4;
    int m0 = blockIdx.x * 32;
    int n0 = wave * 32;

    short8 bh[2][4], bl[2][4];
#pragma unroll
    for (int ct = 0; ct < 2; ct++) {
#pragma unroll
        for (int kc = 0; kc < 4; kc++) {
            size_t off = (size_t)(n0 + ct * 16 + mrow) * HID + kc * 32 + quad * 8;
            bh[ct][kc] = *(const short8*)(Whi + off);
            bl[ct][kc] = *(const short8*)(Wlo + off);
        }
    }

    float4v acc[2][2];
#pragma unroll
    for (int rt = 0; rt < 2; rt++)
#pragma unroll
        for (int ct = 0; ct < 2; ct++) {
            acc[rt][ct].x = 0.f; acc[rt][ct].y = 0.f;
            acc[rt][ct].z = 0.f; acc[rt][ct].w = 0.f;
        }

#pragma unroll
    for (int kc = 0; kc < 4; kc++) {
#pragma unroll
        for (int rt = 0; rt < 2; rt++) {
            size_t aoff = (size_t)(m0 + rt * 16 + mrow) * HID + kc * 32 + quad * 8;
            short8 ah = *(const short8*)(Ahi + aoff);
            short8 al = *(const short8*)(Alo + aoff);
#pragma unroll
            for (int ct = 0; ct < 2; ct++) {
                acc[rt][ct] = __builtin_amdgcn_mfma_f32_16x16x32_bf16(ah, bh[ct][kc], acc[rt][ct], 0, 0, 0);
                acc[rt][ct] = __builtin_amdgcn_mfma_f32_16x16x32_bf16(ah, bl[ct][kc], acc[rt][ct], 0, 0, 0);
                acc[rt][ct] = __builtin_amdgcn_mfma_f32_16x16x32_bf16(al, bh[ct][kc], acc[rt][ct], 0, 0, 0);
                acc[rt][ct] = __builtin_amdgcn_mfma_f32_16x16x32_bf16(al, bl[ct][kc], acc[rt][ct], 0, 0, 0);
            }
        }
    }

#pragma unroll
    for (int rt = 0; rt < 2; rt++) {
#pragma unroll
        for (int ct = 0; ct < 2; ct++) {
            int col = n0 + ct * 16 + mrow;
#pragma unroll
            for (int r = 0; r < 4; r++) {
                int row = m0 + rt * 16 + quad * 4 + r;
                out[(size_t)row * HID + col] = f2bf_rn(acc[rt][ct][r]);
            }
        }
    }
}

// ---------------- gather-aggregate + self-loop + bias + BN + ReLU ----------------
// hl is now bf16 (256 B rows): half the random-gather bytes. Accumulate fp32.
// BF16OUT: write planar bf16 hi/lo (feeds next mm_mfma); else fp32 (feeds pool).

template <bool BF16OUT>
__global__ __launch_bounds__(256) void gather_bn_t(const unsigned short* __restrict__ hl,
                                                   const int* __restrict__ rs,
                                                   const int* __restrict__ esrc,
                                                   const float* __restrict__ ewt,
                                                   const float* __restrict__ dinv,
                                                   const float* __restrict__ b,
                                                   const float* __restrict__ gamma,
                                                   const float* __restrict__ beta,
                                                   const float* __restrict__ mean,
                                                   const float* __restrict__ var,
                                                   float* __restrict__ outf,
                                                   unsigned short* __restrict__ ohi,
                                                   unsigned short* __restrict__ olo) {
    int t = blockIdx.x * blockDim.x + threadIdx.x;
    int lane = t & 31;
    int n = t >> 5;
    if (n >= NN) return;
    const ushort4* hl4 = (const ushort4*)hl;
    float di = dinv[n];
    float4 self = us4tof4(hl4[(size_t)n * 32 + lane]);
    float4 bb = ((const float4*)b)[lane];
    float dsq = di * di;
    float4 acc;
    acc.x = fmaf(self.x, dsq, bb.x);
    acc.y = fmaf(self.y, dsq, bb.y);
    acc.z = fmaf(self.z, dsq, bb.z);
    acc.w = fmaf(self.w, dsq, bb.w);
    int e0 = rs[n], e1 = rs[n + 1];
    int e = e0;
    for (; e + 1 < e1; e += 2) {
        int s0 = esrc[e], s1 = esrc[e + 1];
        float w0 = ewt[e], w1 = ewt[e + 1];
        float4 v0 = us4tof4(hl4[(size_t)s0 * 32 + lane]);
        float4 v1 = us4tof4(hl4[(size_t)s1 * 32 + lane]);
        acc.x = fmaf(v0.x, w0, acc.x); acc.y = fmaf(v0.y, w0, acc.y);
        acc.z = fmaf(v0.z, w0, acc.z); acc.w = fmaf(v0.w, w0, acc.w);
        acc.x = fmaf(v1.x, w1, acc.x); acc.y = fmaf(v1.y, w1, acc.y);
        acc.z = fmaf(v1.z, w1, acc.z); acc.w = fmaf(v1.w, w1, acc.w);
    }
    if (e < e1) {
        int s0 = esrc[e];
        float w0 = ewt[e];
        float4 v0 = us4tof4(hl4[(size_t)s0 * 32 + lane]);
        acc.x = fmaf(v0.x, w0, acc.x); acc.y = fmaf(v0.y, w0, acc.y);
        acc.z = fmaf(v0.z, w0, acc.z); acc.w = fmaf(v0.w, w0, acc.w);
    }
    float4 ga = ((const float4*)gamma)[lane];
    float4 be = ((const float4*)beta)[lane];
    float4 me = ((const float4*)mean)[lane];
    float4 va = ((const float4*)var)[lane];
    float4 o;
    o.x = fmaxf(fmaf(acc.x - me.x, ga.x * rsqrtf(va.x + BN_EPS), be.x), 0.f);
    o.y = fmaxf(fmaf(acc.y - me.y, ga.y * rsqrtf(va.y + BN_EPS), be.y), 0.f);
    o.z = fmaxf(fmaf(acc.z - me.z, ga.z * rsqrtf(va.z + BN_EPS), be.z), 0.f);
    o.w = fmaxf(fmaf(acc.w - me.w, ga.w * rsqrtf(va.w + BN_EPS), be.w), 0.f);
    if (BF16OUT) {
        ushort4 hi4, lo4;
        hi4.x = f2bf_rn(o.x); lo4.x = f2bf_rn(o.x - bf2f(hi4.x));
        hi4.y = f2bf_rn(o.y); lo4.y = f2bf_rn(o.y - bf2f(hi4.y));
        hi4.z = f2bf_rn(o.z); lo4.z = f2bf_rn(o.z - bf2f(hi4.z));
        hi4.w = f2bf_rn(o.w); lo4.w = f2bf_rn(o.w - bf2f(hi4.w));
        ((ushort4*)ohi)[(size_t)n * 32 + lane] = hi4;
        ((ushort4*)olo)[(size_t)n * 32 + lane] = lo4;
    } else {
        ((float4*)outf)[(size_t)n * 32 + lane] = o;
    }
}

// ---------------- fused global mean pool + classifier ----------------

__global__ __launch_bounds__(1024) void poolcls_kernel(const float* __restrict__ h,
                                                       const int* __restrict__ batch,
                                                       const float* __restrict__ pv,
                                                       const float* __restrict__ cw1,
                                                       const float* __restrict__ cb1,
                                                       const float* __restrict__ cw2,
                                                       const float* __restrict__ cb2,
                                                       float* __restrict__ out) {
    int g = blockIdx.x;
    int lane = threadIdx.x & 31;   // float4 index within feature row
    int row = threadIdx.x >> 5;    // 0..31
    __shared__ int se[2];
    __shared__ float emb[192];
    __shared__ float hid[96];
    if (threadIdx.x < 2) {
        int target = g + threadIdx.x;
        int lo = 0, hi = NN;
        while (lo < hi) {
            int mid = (lo + hi) >> 1;
            if (batch[mid] < target) lo = mid + 1; else hi = mid;
        }
        se[threadIdx.x] = lo;
    }
    if (threadIdx.x < 64) emb[128 + threadIdx.x] = pv[threadIdx.x];
    __syncthreads();
    int start = se[0], end = se[1];
    const float4* h4 = (const float4*)h;
    float4 acc = make_float4(0.f, 0.f, 0.f, 0.f);
    for (int n = start + row; n < end; n += 32) {
        float4 v = h4[(size_t)n * 32 + lane];
        acc.x += v.x; acc.y += v.y; acc.z += v.z; acc.w += v.w;
    }
    __shared__ float4 part[32][32];
    part[row][lane] = acc;
    __syncthreads();
#pragma unroll
    for (int off = 16; off >= 1; off >>= 1) {
        if (row < off) {
            float4 a = part[row][lane];
            float4 c = part[row + off][lane];
            a.x += c.x; a.y += c.y; a.z += c.z; a.w += c.w;
            part[row][lane] = a;
        }
        __syncthreads();
    }
    if (row == 0) {
        float inv = 1.0f / fmaxf((float)(end - start), 1.0f);
        float4 a = part[0][lane];
        a.x *= inv; a.y *= inv; a.z *= inv; a.w *= inv;
        ((float4*)emb)[lane] = a;
    }
    __syncthreads();
    int j = threadIdx.x;
    if (j < 96) {
        float a = cb1[j];
        for (int k = 0; k < 192; k++) a = fmaf(emb[k], cw1[k * 96 + j], a);
        hid[j] = fmaxf(a, 0.f) * cw2[j];
    }
    __syncthreads();
    if (j == 0) {
        float s = cb2[0];
        for (int k = 0; k < 96; k++) s += hid[k];
        out[g] = s;
    }
}

extern "C" void kernel_launch(void* const* d_in, const int* in_sizes, int n_in,
                              void* d_out, int out_size, void* d_ws, size_t ws_size,
                              hipStream_t stream) {
    const float* x        = (const float*)d_in[0];
    const int*   eidx     = (const int*)d_in[1];
    const int*   batch    = (const int*)d_in[2];
    const float* pocket   = (const float*)d_in[3];
    const float* W0 = (const float*)d_in[4];
    const float* b0 = (const float*)d_in[5];
    const float* W1 = (const float*)d_in[6];
    const float* b1 = (const float*)d_in[7];
    const float* W2 = (const float*)d_in[8];
    const float* b2 = (const float*)d_in[9];
    const float* bn_gamma = (const float*)d_in[10];
    const float* bn_beta  = (const float*)d_in[11];
    const float* bn_mean  = (const float*)d_in[12];
    const float* bn_var   = (const float*)d_in[13];
    const float* pw1 = (const float*)d_in[14]; const float* pb1 = (const float*)d_in[15];
    const float* pw2 = (const float*)d_in[16]; const float* pb2 = (const float*)d_in[17];
    const float* cw1 = (const float*)d_in[18]; const float* cb1 = (const float*)d_in[19];
    const float* cw2 = (const float*)d_in[20]; const float* cb2 = (const float*)d_in[21];
    float* out = (float*)d_out;

    // Workspace layout (4-byte units):
    float* ws   = (float*)d_ws;
    float* dinv = ws;                                   // NN
    int*   cnt  = (int*)(ws + NN);                      // NN (hist, then cursor)
    int*   rs   = cnt + NN;                             // NN+1
    int*   tsum = rs + NN + 1;                          // 128
    int*   esrc = tsum + 128;                           // NE
    float* ewt  = (float*)(esrc + NE);                  // NE
    float* xa   = ewt + NE;                             // NN*8
    unsigned short* w1hi = (unsigned short*)(xa + (size_t)NN * 8);  // 16384 each
    unsigned short* w1lo = w1hi + HID * HID;
    unsigned short* w2hi = w1lo + HID * HID;
    unsigned short* w2lo = w2hi + HID * HID;
    size_t head = (size_t)NN * 2 + (NN + 1) + 128 + (size_t)NE * 2 + (size_t)NN * 8
                + (4 * HID * HID) / 2;                  // 4 ushort arrays = 2*HID*HID floats
    head = (head + 3) & ~(size_t)3;                     // 16B align
    // R1 region: NN*HID floats. Aliased: during layers 1/2 it holds bf16 hi/lo
    // planes (Ahi | Alo); final gather writes fp32 Cf here.
    float* R1   = ws + head;
    unsigned short* Ahi = (unsigned short*)R1;          // NN*HID ushort
    unsigned short* Alo = Ahi + (size_t)NN * HID;       // NN*HID ushort
    float* Cf   = R1;                                   // NN*HID float (same bytes)
    unsigned short* B = (unsigned short*)(R1 + (size_t)NN * HID);  // NN*HID ushort (bf16 hl)
    float* pv   = R1 + (size_t)NN * HID + (size_t)NN * HID / 2;    // 64

    const int* srcp = eidx;
    const int* dstp = eidx + NE;

    // ---- build CSR (by dst) + dinv + edge weights; split W1/W2 + pocket ----
    hipMemsetAsync(cnt, 0, NN * sizeof(int), stream);
    hist_kernel<<<(NE + 255) / 256, 256, 0, stream>>>(dstp, cnt);
    scan_a<<<NTILES, 256, 0, stream>>>(cnt, rs, tsum, dinv);
    scan_b<<<1, 128, 0, stream>>>(tsum);
    scan_c<<<NTILES, 256, 0, stream>>>(rs, tsum, cnt);  // cnt becomes cursor
    bucket_kernel<<<(NE + 255) / 256, 256, 0, stream>>>(srcp, dstp, dinv, cnt, esrc, ewt);
    prep_kernel<<<65, 256, 0, stream>>>(W1, W2, w1hi, w1lo, w2hi, w2lo,
                                        pocket, pw1, pb1, pw2, pb2, pv);

    // ---- layer 0: aggregate x, then transform -> bf16 hi/lo planes ----
    xagg_kernel<<<(NN * 8 + 255) / 256, 256, 0, stream>>>(x, rs, esrc, ewt, dinv, xa);
    l0_transform<<<2048, 256, 0, stream>>>(xa, W0, b0,
                                           bn_gamma + 0 * HID, bn_beta + 0 * HID,
                                           bn_mean + 0 * HID, bn_var + 0 * HID, Ahi, Alo);

    const int MM_BLOCKS = NN / 32;  // 3125 (NN % 32 == 0)

    // ---- layer 1 ----
    mm_mfma<<<MM_BLOCKS, 256, 0, stream>>>(Ahi, Alo, w1hi, w1lo, B);
    gather_bn_t<true><<<(NN * 32 + 255) / 256, 256, 0, stream>>>(
        B, rs, esrc, ewt, dinv, b1,
        bn_gamma + 1 * HID, bn_beta + 1 * HID, bn_mean + 1 * HID, bn_var + 1 * HID,
        nullptr, Ahi, Alo);
    // ---- layer 2 ----
    mm_mfma<<<MM_BLOCKS, 256, 0, stream>>>(Ahi, Alo, w2hi, w2lo, B);
    gather_bn_t<false><<<(NN * 32 + 255) / 256, 256, 0, stream>>>(
        B, rs, esrc, ewt, dinv, b2,
        bn_gamma + 2 * HID, bn_beta + 2 * HID, bn_mean + 2 * HID, bn_var + 2 * HID,
        Cf, nullptr, nullptr);

    // fused pool + classifier
    poolcls_kernel<<<NG, 1024, 0, stream>>>(Cf, batch, pv, cw1, cb1, cw2, cb2, out);
}

// Round 11
// 380.497 us; speedup vs baseline: 1.2470x; 1.0604x over previous
//
#include <hip/hip_runtime.h>

// Problem constants (match reference setup_inputs)
#define NN 100000
#define NE 600000
#define NG 256
#define HID 128
#define BN_EPS 1e-5f

#define SCAN_TILE 1024
#define NTILES ((NN + SCAN_TILE - 1) / SCAN_TILE)  // 98

typedef __attribute__((ext_vector_type(8))) short short8;
typedef __attribute__((ext_vector_type(4))) float float4v;

// bf16 round-to-nearest-even helpers
__device__ __forceinline__ unsigned short f2bf_rn(float f) {
    unsigned u = __float_as_uint(f);
    unsigned r = u + 0x7FFFu + ((u >> 16) & 1u);
    return (unsigned short)(r >> 16);
}
__device__ __forceinline__ float bf2f(unsigned short h) {
    return __uint_as_float((unsigned)h << 16);
}
__device__ __forceinline__ float4 us4tof4(ushort4 u) {
    return make_float4(bf2f(u.x), bf2f(u.y), bf2f(u.z), bf2f(u.w));
}

// ---------------- histogram of dst (in-degree) ----------------

__global__ __launch_bounds__(256) void hist_kernel(const int* __restrict__ dst, int* __restrict__ cnt) {
    int e = blockIdx.x * blockDim.x + threadIdx.x;
    if (e < NE) atomicAdd(&cnt[dst[e]], 1);
}

// ---------------- 2-level exclusive scan of cnt -> row_start (+ dinv fused) ----------------

__global__ __launch_bounds__(256) void scan_a(const int* __restrict__ cnt, int* __restrict__ rs,
                                              int* __restrict__ tsum, float* __restrict__ dinv) {
    __shared__ int s[256];
    int t = threadIdx.x;
    int base = blockIdx.x * SCAN_TILE;
    int idx = base + t * 4;
    int v0 = (idx + 0 < NN) ? cnt[idx + 0] : 0;
    int v1 = (idx + 1 < NN) ? cnt[idx + 1] : 0;
    int v2 = (idx + 2 < NN) ? cnt[idx + 2] : 0;
    int v3 = (idx + 3 < NN) ? cnt[idx + 3] : 0;
    if (idx + 0 < NN) dinv[idx + 0] = rsqrtf((float)v0 + 1.0f);
    if (idx + 1 < NN) dinv[idx + 1] = rsqrtf((float)v1 + 1.0f);
    if (idx + 2 < NN) dinv[idx + 2] = rsqrtf((float)v2 + 1.0f);
    if (idx + 3 < NN) dinv[idx + 3] = rsqrtf((float)v3 + 1.0f);
    int local = v0 + v1 + v2 + v3;
    s[t] = local;
    __syncthreads();
    for (int off = 1; off < 256; off <<= 1) {
        int x = (t >= off) ? s[t - off] : 0;
        __syncthreads();
        s[t] += x;
        __syncthreads();
    }
    int pre = s[t] - local;  // exclusive prefix within tile
    if (t == 255) tsum[blockIdx.x] = s[255];
    if (idx + 0 < NN) rs[idx + 0] = pre; pre += v0;
    if (idx + 1 < NN) rs[idx + 1] = pre; pre += v1;
    if (idx + 2 < NN) rs[idx + 2] = pre; pre += v2;
    if (idx + 3 < NN) rs[idx + 3] = pre;
}

__global__ __launch_bounds__(128) void scan_b(int* __restrict__ tsum) {
    __shared__ int s[128];
    int t = threadIdx.x;
    int v = (t < NTILES) ? tsum[t] : 0;
    s[t] = v;
    __syncthreads();
    for (int off = 1; off < 128; off <<= 1) {
        int x = (t >= off) ? s[t - off] : 0;
        __syncthreads();
        s[t] += x;
        __syncthreads();
    }
    if (t < NTILES) tsum[t] = s[t] - v;  // exclusive
}

__global__ __launch_bounds__(256) void scan_c(int* __restrict__ rs, const int* __restrict__ tsum,
                                              int* __restrict__ cursor) {
    int t = threadIdx.x;
    int base = blockIdx.x * SCAN_TILE;
    int off = tsum[blockIdx.x];
    for (int k = 0; k < 4; k++) {
        int idx = base + t * 4 + k;
        if (idx < NN) {
            int v = rs[idx] + off;
            rs[idx] = v;
            cursor[idx] = v;
        }
    }
    if (blockIdx.x == 0 && t == 0) rs[NN] = NE;
}

// ---------------- bucket edges by dst (also precompute edge weights) ----------------

__global__ __launch_bounds__(256) void bucket_kernel(const int* __restrict__ src, const int* __restrict__ dst,
                                                     const float* __restrict__ dinv,
                                                     int* __restrict__ cursor,
                                                     int* __restrict__ esrc, float* __restrict__ ewt) {
    int e = blockIdx.x * blockDim.x + threadIdx.x;
    if (e < NE) {
        int s = src[e], d = dst[e];
        int pos = atomicAdd(&cursor[d], 1);
        esrc[pos] = s;
        ewt[pos] = dinv[s] * dinv[d];
    }
}

// ---------------- prep: split W1/W2 (transposed) + pocket MLP ----------------

__global__ __launch_bounds__(256) void prep_kernel(const float* __restrict__ W1, const float* __restrict__ W2,
                                                   unsigned short* __restrict__ w1hi, unsigned short* __restrict__ w1lo,
                                                   unsigned short* __restrict__ w2hi, unsigned short* __restrict__ w2lo,
                                                   const float* __restrict__ pocket,
                                                   const float* __restrict__ pw1, const float* __restrict__ pb1,
                                                   const float* __restrict__ pw2, const float* __restrict__ pb2,
                                                   float* __restrict__ pv) {
    if (blockIdx.x < 64) {
        int t = blockIdx.x * 256 + threadIdx.x;
        int k = t >> 7, n = t & 127;      // W[k][n]
        int to = n * HID + k;             // Wt[n][k]
        float v1 = W1[t];
        unsigned short h1 = f2bf_rn(v1);
        w1hi[to] = h1;
        w1lo[to] = f2bf_rn(v1 - bf2f(h1));
        float v2 = W2[t];
        unsigned short h2 = f2bf_rn(v2);
        w2hi[to] = h2;
        w2lo[to] = f2bf_rn(v2 - bf2f(h2));
    } else {
        __shared__ float t1[64];
        int j = threadIdx.x;
        if (j < 64) {
            float acc = pb1[j];
            for (int k = 0; k < 28; k++) acc = fmaf(pocket[k], pw1[k * 64 + j], acc);
            t1[j] = fmaxf(acc, 0.f);
        }
        __syncthreads();
        if (j < 64) {
            float acc2 = pb2[j];
            for (int k = 0; k < 64; k++) acc2 = fmaf(t1[k], pw2[k * 64 + j], acc2);
            pv[j] = acc2;
        }
    }
}

// ---------------- layer 0 part A: aggregate raw x (7-dim) -> xa [NN,8] ----------------

__global__ __launch_bounds__(256) void xagg_kernel(const float* __restrict__ x,
                                                   const int* __restrict__ rs,
                                                   const int* __restrict__ esrc,
                                                   const float* __restrict__ ewt,
                                                   const float* __restrict__ dinv,
                                                   float* __restrict__ xa) {
    int t = blockIdx.x * blockDim.x + threadIdx.x;
    int f = t & 7;
    int n = t >> 3;
    if (n >= NN) return;
    float acc = 0.f;
    if (f < 7) {
        float di = dinv[n];
        acc = x[n * 7 + f] * di * di;
        int e0 = rs[n], e1 = rs[n + 1];
        int e = e0;
        for (; e + 1 < e1; e += 2) {
            int s0 = esrc[e], s1 = esrc[e + 1];
            float w0 = ewt[e], w1 = ewt[e + 1];
            float a0 = x[s0 * 7 + f];
            float a1 = x[s1 * 7 + f];
            acc = fmaf(a0, w0, acc);
            acc = fmaf(a1, w1, acc);
        }
        if (e < e1) acc = fmaf(x[esrc[e] * 7 + f], ewt[e], acc);
    }
    xa[n * 8 + f] = acc;
}

// ---------------- layer 0 part B: xa @ W0 + b -> BN -> ReLU -> bf16 (single plane) ----------------

__global__ __launch_bounds__(256) void l0_transform(const float* __restrict__ xa,
                                                    const float* __restrict__ W,
                                                    const float* __restrict__ b,
                                                    const float* __restrict__ gamma,
                                                    const float* __restrict__ beta,
                                                    const float* __restrict__ mean,
                                                    const float* __restrict__ var,
                                                    unsigned short* __restrict__ ohi) {
    int c4 = threadIdx.x & 31;   // feature group: j = c4*4 + i
    int r  = threadIdx.x >> 5;   // node within 8-group
    float w[7][4];
#pragma unroll
    for (int k = 0; k < 7; k++)
#pragma unroll
        for (int i = 0; i < 4; i++) w[k][i] = W[k * HID + c4 * 4 + i];
    float4 bb = ((const float4*)b)[c4];
    float4 ga = ((const float4*)gamma)[c4];
    float4 be = ((const float4*)beta)[c4];
    float4 me = ((const float4*)mean)[c4];
    float4 va = ((const float4*)var)[c4];
    float4 sc;
    sc.x = ga.x * rsqrtf(va.x + BN_EPS);
    sc.y = ga.y * rsqrtf(va.y + BN_EPS);
    sc.z = ga.z * rsqrtf(va.z + BN_EPS);
    sc.w = ga.w * rsqrtf(va.w + BN_EPS);
    __shared__ float s[8][8];
    for (int n0 = blockIdx.x * 8; n0 < NN; n0 += gridDim.x * 8) {
        __syncthreads();
        if (threadIdx.x < 64) s[threadIdx.x >> 3][threadIdx.x & 7] = xa[n0 * 8 + threadIdx.x];
        __syncthreads();
        float o0 = bb.x, o1 = bb.y, o2 = bb.z, o3 = bb.w;
#pragma unroll
        for (int k = 0; k < 7; k++) {
            float xv = s[r][k];
            o0 = fmaf(xv, w[k][0], o0);
            o1 = fmaf(xv, w[k][1], o1);
            o2 = fmaf(xv, w[k][2], o2);
            o3 = fmaf(xv, w[k][3], o3);
        }
        ushort4 hi4;
        hi4.x = f2bf_rn(fmaxf(fmaf(o0 - me.x, sc.x, be.x), 0.f));
        hi4.y = f2bf_rn(fmaxf(fmaf(o1 - me.y, sc.y, be.y), 0.f));
        hi4.z = f2bf_rn(fmaxf(fmaf(o2 - me.z, sc.z, be.z), 0.f));
        hi4.w = f2bf_rn(fmaxf(fmaf(o3 - me.w, sc.w, be.w), 0.f));
        *(ushort4*)(ohi + (size_t)(n0 + r) * HID + c4 * 4) = hi4;
    }
}

// ---------------- layers 1/2 matmul via MFMA ----------------
// A: single bf16 plane (activation quant errors average out in the pool).
// W: split hi+lo (systematic error would NOT average out) -> 2 MFMAs per frag.
// Output quantized to bf16 (halves the downstream gather bytes).

__global__ __launch_bounds__(256) void mm_mfma(const unsigned short* __restrict__ A,
                                               const unsigned short* __restrict__ Whi,
                                               const unsigned short* __restrict__ Wlo,
                                               unsigned short* __restrict__ out) {
    int wave = threadIdx.x >> 6;
    int lane = threadIdx.x & 63;
    int mrow = lane & 15;
    int quad = lane >> 4;
    int m0 = blockIdx.x * 32;
    int n0 = wave * 32;

    short8 bh[2][4], bl[2][4];
#pragma unroll
    for (int ct = 0; ct < 2; ct++) {
#pragma unroll
        for (int kc = 0; kc < 4; kc++) {
            size_t off = (size_t)(n0 + ct * 16 + mrow) * HID + kc * 32 + quad * 8;
            bh[ct][kc] = *(const short8*)(Whi + off);
            bl[ct][kc] = *(const short8*)(Wlo + off);
        }
    }

    float4v acc[2][2];
#pragma unroll
    for (int rt = 0; rt < 2; rt++)
#pragma unroll
        for (int ct = 0; ct < 2; ct++) {
            acc[rt][ct].x = 0.f; acc[rt][ct].y = 0.f;
            acc[rt][ct].z = 0.f; acc[rt][ct].w = 0.f;
        }

#pragma unroll
    for (int kc = 0; kc < 4; kc++) {
#pragma unroll
        for (int rt = 0; rt < 2; rt++) {
            size_t aoff = (size_t)(m0 + rt * 16 + mrow) * HID + kc * 32 + quad * 8;
            short8 ah = *(const short8*)(A + aoff);
#pragma unroll
            for (int ct = 0; ct < 2; ct++) {
                acc[rt][ct] = __builtin_amdgcn_mfma_f32_16x16x32_bf16(ah, bh[ct][kc], acc[rt][ct], 0, 0, 0);
                acc[rt][ct] = __builtin_amdgcn_mfma_f32_16x16x32_bf16(ah, bl[ct][kc], acc[rt][ct], 0, 0, 0);
            }
        }
    }

#pragma unroll
    for (int rt = 0; rt < 2; rt++) {
#pragma unroll
        for (int ct = 0; ct < 2; ct++) {
            int col = n0 + ct * 16 + mrow;
#pragma unroll
            for (int r = 0; r < 4; r++) {
                int row = m0 + rt * 16 + quad * 4 + r;
                out[(size_t)row * HID + col] = f2bf_rn(acc[rt][ct][r]);
            }
        }
    }
}

// ---------------- gather-aggregate + self-loop + bias + BN + ReLU ----------------
// hl bf16 rows (256 B gather). BF16OUT: single bf16 plane; else fp32 for pool.

template <bool BF16OUT>
__global__ __launch_bounds__(256) void gather_bn_t(const unsigned short* __restrict__ hl,
                                                   const int* __restrict__ rs,
                                                   const int* __restrict__ esrc,
                                                   const float* __restrict__ ewt,
                                                   const float* __restrict__ dinv,
                                                   const float* __restrict__ b,
                                                   const float* __restrict__ gamma,
                                                   const float* __restrict__ beta,
                                                   const float* __restrict__ mean,
                                                   const float* __restrict__ var,
                                                   float* __restrict__ outf,
                                                   unsigned short* __restrict__ ohi) {
    int t = blockIdx.x * blockDim.x + threadIdx.x;
    int lane = t & 31;
    int n = t >> 5;
    if (n >= NN) return;
    const ushort4* hl4 = (const ushort4*)hl;
    float di = dinv[n];
    float4 self = us4tof4(hl4[(size_t)n * 32 + lane]);
    float4 bb = ((const float4*)b)[lane];
    float dsq = di * di;
    float4 acc;
    acc.x = fmaf(self.x, dsq, bb.x);
    acc.y = fmaf(self.y, dsq, bb.y);
    acc.z = fmaf(self.z, dsq, bb.z);
    acc.w = fmaf(self.w, dsq, bb.w);
    int e0 = rs[n], e1 = rs[n + 1];
    int e = e0;
    for (; e + 1 < e1; e += 2) {
        int s0 = esrc[e], s1 = esrc[e + 1];
        float w0 = ewt[e], w1 = ewt[e + 1];
        float4 v0 = us4tof4(hl4[(size_t)s0 * 32 + lane]);
        float4 v1 = us4tof4(hl4[(size_t)s1 * 32 + lane]);
        acc.x = fmaf(v0.x, w0, acc.x); acc.y = fmaf(v0.y, w0, acc.y);
        acc.z = fmaf(v0.z, w0, acc.z); acc.w = fmaf(v0.w, w0, acc.w);
        acc.x = fmaf(v1.x, w1, acc.x); acc.y = fmaf(v1.y, w1, acc.y);
        acc.z = fmaf(v1.z, w1, acc.z); acc.w = fmaf(v1.w, w1, acc.w);
    }
    if (e < e1) {
        int s0 = esrc[e];
        float w0 = ewt[e];
        float4 v0 = us4tof4(hl4[(size_t)s0 * 32 + lane]);
        acc.x = fmaf(v0.x, w0, acc.x); acc.y = fmaf(v0.y, w0, acc.y);
        acc.z = fmaf(v0.z, w0, acc.z); acc.w = fmaf(v0.w, w0, acc.w);
    }
    float4 ga = ((const float4*)gamma)[lane];
    float4 be = ((const float4*)beta)[lane];
    float4 me = ((const float4*)mean)[lane];
    float4 va = ((const float4*)var)[lane];
    float4 o;
    o.x = fmaxf(fmaf(acc.x - me.x, ga.x * rsqrtf(va.x + BN_EPS), be.x), 0.f);
    o.y = fmaxf(fmaf(acc.y - me.y, ga.y * rsqrtf(va.y + BN_EPS), be.y), 0.f);
    o.z = fmaxf(fmaf(acc.z - me.z, ga.z * rsqrtf(va.z + BN_EPS), be.z), 0.f);
    o.w = fmaxf(fmaf(acc.w - me.w, ga.w * rsqrtf(va.w + BN_EPS), be.w), 0.f);
    if (BF16OUT) {
        ushort4 hi4;
        hi4.x = f2bf_rn(o.x);
        hi4.y = f2bf_rn(o.y);
        hi4.z = f2bf_rn(o.z);
        hi4.w = f2bf_rn(o.w);
        ((ushort4*)ohi)[(size_t)n * 32 + lane] = hi4;
    } else {
        ((float4*)outf)[(size_t)n * 32 + lane] = o;
    }
}

// ---------------- fused global mean pool + classifier ----------------

__global__ __launch_bounds__(1024) void poolcls_kernel(const float* __restrict__ h,
                                                       const int* __restrict__ batch,
                                                       const float* __restrict__ pv,
                                                       const float* __restrict__ cw1,
                                                       const float* __restrict__ cb1,
                                                       const float* __restrict__ cw2,
                                                       const float* __restrict__ cb2,
                                                       float* __restrict__ out) {
    int g = blockIdx.x;
    int lane = threadIdx.x & 31;   // float4 index within feature row
    int row = threadIdx.x >> 5;    // 0..31
    __shared__ int se[2];
    __shared__ float emb[192];
    __shared__ float hid[96];
    if (threadIdx.x < 2) {
        int target = g + threadIdx.x;
        int lo = 0, hi = NN;
        while (lo < hi) {
            int mid = (lo + hi) >> 1;
            if (batch[mid] < target) lo = mid + 1; else hi = mid;
        }
        se[threadIdx.x] = lo;
    }
    if (threadIdx.x < 64) emb[128 + threadIdx.x] = pv[threadIdx.x];
    __syncthreads();
    int start = se[0], end = se[1];
    const float4* h4 = (const float4*)h;
    float4 acc = make_float4(0.f, 0.f, 0.f, 0.f);
    for (int n = start + row; n < end; n += 32) {
        float4 v = h4[(size_t)n * 32 + lane];
        acc.x += v.x; acc.y += v.y; acc.z += v.z; acc.w += v.w;
    }
    __shared__ float4 part[32][32];
    part[row][lane] = acc;
    __syncthreads();
#pragma unroll
    for (int off = 16; off >= 1; off >>= 1) {
        if (row < off) {
            float4 a = part[row][lane];
            float4 c = part[row + off][lane];
            a.x += c.x; a.y += c.y; a.z += c.z; a.w += c.w;
            part[row][lane] = a;
        }
        __syncthreads();
    }
    if (row == 0) {
        float inv = 1.0f / fmaxf((float)(end - start), 1.0f);
        float4 a = part[0][lane];
        a.x *= inv; a.y *= inv; a.z *= inv; a.w *= inv;
        ((float4*)emb)[lane] = a;
    }
    __syncthreads();
    int j = threadIdx.x;
    if (j < 96) {
        float a = cb1[j];
        for (int k = 0; k < 192; k++) a = fmaf(emb[k], cw1[k * 96 + j], a);
        hid[j] = fmaxf(a, 0.f) * cw2[j];
    }
    __syncthreads();
    if (j == 0) {
        float s = cb2[0];
        for (int k = 0; k < 96; k++) s += hid[k];
        out[g] = s;
    }
}

extern "C" void kernel_launch(void* const* d_in, const int* in_sizes, int n_in,
                              void* d_out, int out_size, void* d_ws, size_t ws_size,
                              hipStream_t stream) {
    const float* x        = (const float*)d_in[0];
    const int*   eidx     = (const int*)d_in[1];
    const int*   batch    = (const int*)d_in[2];
    const float* pocket   = (const float*)d_in[3];
    const float* W0 = (const float*)d_in[4];
    const float* b0 = (const float*)d_in[5];
    const float* W1 = (const float*)d_in[6];
    const float* b1 = (const float*)d_in[7];
    const float* W2 = (const float*)d_in[8];
    const float* b2 = (const float*)d_in[9];
    const float* bn_gamma = (const float*)d_in[10];
    const float* bn_beta  = (const float*)d_in[11];
    const float* bn_mean  = (const float*)d_in[12];
    const float* bn_var   = (const float*)d_in[13];
    const float* pw1 = (const float*)d_in[14]; const float* pb1 = (const float*)d_in[15];
    const float* pw2 = (const float*)d_in[16]; const float* pb2 = (const float*)d_in[17];
    const float* cw1 = (const float*)d_in[18]; const float* cb1 = (const float*)d_in[19];
    const float* cw2 = (const float*)d_in[20]; const float* cb2 = (const float*)d_in[21];
    float* out = (float*)d_out;

    // Workspace layout (4-byte units):
    float* ws   = (float*)d_ws;
    float* dinv = ws;                                   // NN
    int*   cnt  = (int*)(ws + NN);                      // NN (hist, then cursor)
    int*   rs   = cnt + NN;                             // NN+1
    int*   tsum = rs + NN + 1;                          // 128
    int*   esrc = tsum + 128;                           // NE
    float* ewt  = (float*)(esrc + NE);                  // NE
    float* xa   = ewt + NE;                             // NN*8
    unsigned short* w1hi = (unsigned short*)(xa + (size_t)NN * 8);  // 16384 each
    unsigned short* w1lo = w1hi + HID * HID;
    unsigned short* w2hi = w1lo + HID * HID;
    unsigned short* w2lo = w2hi + HID * HID;
    size_t head = (size_t)NN * 2 + (NN + 1) + 128 + (size_t)NE * 2 + (size_t)NN * 8
                + (4 * HID * HID) / 2;                  // 4 ushort arrays = 2*HID*HID floats
    head = (head + 3) & ~(size_t)3;                     // 16B align
    // R1 region (NN*HID floats): holds bf16 A plane during layers 1/2;
    // final gather writes fp32 Cf over the same bytes (A no longer needed).
    float* R1   = ws + head;
    unsigned short* A = (unsigned short*)R1;            // NN*HID ushort (bf16 act)
    float* Cf   = R1;                                   // NN*HID float (aliases A)
    unsigned short* B = (unsigned short*)(R1 + (size_t)NN * HID);  // NN*HID ushort (bf16 hl)
    float* pv   = R1 + (size_t)NN * HID + (size_t)NN * HID / 2;    // 64

    const int* srcp = eidx;
    const int* dstp = eidx + NE;

    // ---- build CSR (by dst) + dinv + edge weights; split W1/W2 + pocket ----
    hipMemsetAsync(cnt, 0, NN * sizeof(int), stream);
    hist_kernel<<<(NE + 255) / 256, 256, 0, stream>>>(dstp, cnt);
    scan_a<<<NTILES, 256, 0, stream>>>(cnt, rs, tsum, dinv);
    scan_b<<<1, 128, 0, stream>>>(tsum);
    scan_c<<<NTILES, 256, 0, stream>>>(rs, tsum, cnt);  // cnt becomes cursor
    bucket_kernel<<<(NE + 255) / 256, 256, 0, stream>>>(srcp, dstp, dinv, cnt, esrc, ewt);
    prep_kernel<<<65, 256, 0, stream>>>(W1, W2, w1hi, w1lo, w2hi, w2lo,
                                        pocket, pw1, pb1, pw2, pb2, pv);

    // ---- layer 0: aggregate x, then transform -> bf16 plane A ----
    xagg_kernel<<<(NN * 8 + 255) / 256, 256, 0, stream>>>(x, rs, esrc, ewt, dinv, xa);
    l0_transform<<<2048, 256, 0, stream>>>(xa, W0, b0,
                                           bn_gamma + 0 * HID, bn_beta + 0 * HID,
                                           bn_mean + 0 * HID, bn_var + 0 * HID, A);

    const int MM_BLOCKS = NN / 32;  // 3125 (NN % 32 == 0)

    // ---- layer 1 ----
    mm_mfma<<<MM_BLOCKS, 256, 0, stream>>>(A, w1hi, w1lo, B);
    gather_bn_t<true><<<(NN * 32 + 255) / 256, 256, 0, stream>>>(
        B, rs, esrc, ewt, dinv, b1,
        bn_gamma + 1 * HID, bn_beta + 1 * HID, bn_mean + 1 * HID, bn_var + 1 * HID,
        nullptr, A);
    // ---- layer 2 ----
    mm_mfma<<<MM_BLOCKS, 256, 0, stream>>>(A, w2hi, w2lo, B);
    gather_bn_t<false><<<(NN * 32 + 255) / 256, 256, 0, stream>>>(
        B, rs, esrc, ewt, dinv, b2,
        bn_gamma + 2 * HID, bn_beta + 2 * HID, bn_mean + 2 * HID, bn_var + 2 * HID,
        Cf, nullptr);

    // fused pool + classifier
    poolcls_kernel<<<NG, 1024, 0, stream>>>(Cf, batch, pv, cw1, cb1, cw2, cb2, out);
}

// Round 12
// 342.554 us; speedup vs baseline: 1.3852x; 1.1108x over previous
//
#include <hip/hip_runtime.h>

// Problem constants (match reference setup_inputs)
#define NN 100000
#define NE 600000
#define NG 256
#define HID 128
#define BN_EPS 1e-5f

#define SCAN_TILE 1024
#define NTILES ((NN + SCAN_TILE - 1) / SCAN_TILE)  // 98
#define MM_TILES (NN / 32)                          // 3125 (NN % 32 == 0)

typedef __attribute__((ext_vector_type(8))) short short8;
typedef __attribute__((ext_vector_type(4))) float float4v;

// bf16 round-to-nearest-even helpers
__device__ __forceinline__ unsigned short f2bf_rn(float f) {
    unsigned u = __float_as_uint(f);
    unsigned r = u + 0x7FFFu + ((u >> 16) & 1u);
    return (unsigned short)(r >> 16);
}
__device__ __forceinline__ float bf2f(unsigned short h) {
    return __uint_as_float((unsigned)h << 16);
}
__device__ __forceinline__ void unpack8(uint4 u, float* f) {
    f[0] = __uint_as_float(u.x << 16); f[1] = __uint_as_float(u.x & 0xFFFF0000u);
    f[2] = __uint_as_float(u.y << 16); f[3] = __uint_as_float(u.y & 0xFFFF0000u);
    f[4] = __uint_as_float(u.z << 16); f[5] = __uint_as_float(u.z & 0xFFFF0000u);
    f[6] = __uint_as_float(u.w << 16); f[7] = __uint_as_float(u.w & 0xFFFF0000u);
}

// ---------------- histogram of dst (in-degree) ----------------

__global__ __launch_bounds__(256) void hist_kernel(const int* __restrict__ dst, int* __restrict__ cnt) {
    int e = blockIdx.x * blockDim.x + threadIdx.x;
    if (e < NE) atomicAdd(&cnt[dst[e]], 1);
}

// ---------------- 2-level exclusive scan of cnt -> row_start (+ dinv fused) ----------------

__global__ __launch_bounds__(256) void scan_a(const int* __restrict__ cnt, int* __restrict__ rs,
                                              int* __restrict__ tsum, float* __restrict__ dinv) {
    __shared__ int s[256];
    int t = threadIdx.x;
    int base = blockIdx.x * SCAN_TILE;
    int idx = base + t * 4;
    int v0 = (idx + 0 < NN) ? cnt[idx + 0] : 0;
    int v1 = (idx + 1 < NN) ? cnt[idx + 1] : 0;
    int v2 = (idx + 2 < NN) ? cnt[idx + 2] : 0;
    int v3 = (idx + 3 < NN) ? cnt[idx + 3] : 0;
    if (idx + 0 < NN) dinv[idx + 0] = rsqrtf((float)v0 + 1.0f);
    if (idx + 1 < NN) dinv[idx + 1] = rsqrtf((float)v1 + 1.0f);
    if (idx + 2 < NN) dinv[idx + 2] = rsqrtf((float)v2 + 1.0f);
    if (idx + 3 < NN) dinv[idx + 3] = rsqrtf((float)v3 + 1.0f);
    int local = v0 + v1 + v2 + v3;
    s[t] = local;
    __syncthreads();
    for (int off = 1; off < 256; off <<= 1) {
        int x = (t >= off) ? s[t - off] : 0;
        __syncthreads();
        s[t] += x;
        __syncthreads();
    }
    int pre = s[t] - local;  // exclusive prefix within tile
    if (t == 255) tsum[blockIdx.x] = s[255];
    if (idx + 0 < NN) rs[idx + 0] = pre; pre += v0;
    if (idx + 1 < NN) rs[idx + 1] = pre; pre += v1;
    if (idx + 2 < NN) rs[idx + 2] = pre; pre += v2;
    if (idx + 3 < NN) rs[idx + 3] = pre;
}

__global__ __launch_bounds__(128) void scan_b(int* __restrict__ tsum) {
    __shared__ int s[128];
    int t = threadIdx.x;
    int v = (t < NTILES) ? tsum[t] : 0;
    s[t] = v;
    __syncthreads();
    for (int off = 1; off < 128; off <<= 1) {
        int x = (t >= off) ? s[t - off] : 0;
        __syncthreads();
        s[t] += x;
        __syncthreads();
    }
    if (t < NTILES) tsum[t] = s[t] - v;  // exclusive
}

__global__ __launch_bounds__(256) void scan_c(int* __restrict__ rs, const int* __restrict__ tsum,
                                              int* __restrict__ cursor) {
    int t = threadIdx.x;
    int base = blockIdx.x * SCAN_TILE;
    int off = tsum[blockIdx.x];
    for (int k = 0; k < 4; k++) {
        int idx = base + t * 4 + k;
        if (idx < NN) {
            int v = rs[idx] + off;
            rs[idx] = v;
            cursor[idx] = v;
        }
    }
    if (blockIdx.x == 0 && t == 0) rs[NN] = NE;
}

// ---------------- bucket edges by dst (also precompute edge weights) ----------------

__global__ __launch_bounds__(256) void bucket_kernel(const int* __restrict__ src, const int* __restrict__ dst,
                                                     const float* __restrict__ dinv,
                                                     int* __restrict__ cursor,
                                                     int* __restrict__ esrc, float* __restrict__ ewt) {
    int e = blockIdx.x * blockDim.x + threadIdx.x;
    if (e < NE) {
        int s = src[e], d = dst[e];
        int pos = atomicAdd(&cursor[d], 1);
        esrc[pos] = s;
        ewt[pos] = dinv[s] * dinv[d];
    }
}

// ---------------- prep: split W1/W2 (transposed) + pocket MLP ----------------

__global__ __launch_bounds__(256) void prep_kernel(const float* __restrict__ W1, const float* __restrict__ W2,
                                                   unsigned short* __restrict__ w1hi, unsigned short* __restrict__ w1lo,
                                                   unsigned short* __restrict__ w2hi, unsigned short* __restrict__ w2lo,
                                                   const float* __restrict__ pocket,
                                                   const float* __restrict__ pw1, const float* __restrict__ pb1,
                                                   const float* __restrict__ pw2, const float* __restrict__ pb2,
                                                   float* __restrict__ pv) {
    if (blockIdx.x < 64) {
        int t = blockIdx.x * 256 + threadIdx.x;
        int k = t >> 7, n = t & 127;      // W[k][n]
        int to = n * HID + k;             // Wt[n][k]
        float v1 = W1[t];
        unsigned short h1 = f2bf_rn(v1);
        w1hi[to] = h1;
        w1lo[to] = f2bf_rn(v1 - bf2f(h1));
        float v2 = W2[t];
        unsigned short h2 = f2bf_rn(v2);
        w2hi[to] = h2;
        w2lo[to] = f2bf_rn(v2 - bf2f(h2));
    } else {
        __shared__ float t1[64];
        int j = threadIdx.x;
        if (j < 64) {
            float acc = pb1[j];
            for (int k = 0; k < 28; k++) acc = fmaf(pocket[k], pw1[k * 64 + j], acc);
            t1[j] = fmaxf(acc, 0.f);
        }
        __syncthreads();
        if (j < 64) {
            float acc2 = pb2[j];
            for (int k = 0; k < 64; k++) acc2 = fmaf(t1[k], pw2[k * 64 + j], acc2);
            pv[j] = acc2;
        }
    }
}

// ---------------- layer 0 part A: aggregate raw x (7-dim) -> xa [NN,8] ----------------

__global__ __launch_bounds__(256) void xagg_kernel(const float* __restrict__ x,
                                                   const int* __restrict__ rs,
                                                   const int* __restrict__ esrc,
                                                   const float* __restrict__ ewt,
                                                   const float* __restrict__ dinv,
                                                   float* __restrict__ xa) {
    int t = blockIdx.x * blockDim.x + threadIdx.x;
    int f = t & 7;
    int n = t >> 3;
    if (n >= NN) return;
    float acc = 0.f;
    if (f < 7) {
        float di = dinv[n];
        acc = x[n * 7 + f] * di * di;
        int e0 = rs[n], e1 = rs[n + 1];
        int e = e0;
        for (; e + 1 < e1; e += 2) {
            int s0 = esrc[e], s1 = esrc[e + 1];
            float w0 = ewt[e], w1 = ewt[e + 1];
            float a0 = x[s0 * 7 + f];
            float a1 = x[s1 * 7 + f];
            acc = fmaf(a0, w0, acc);
            acc = fmaf(a1, w1, acc);
        }
        if (e < e1) acc = fmaf(x[esrc[e] * 7 + f], ewt[e], acc);
    }
    xa[n * 8 + f] = acc;
}

// ---------------- layer 0 part B: xa @ W0 + b -> BN -> ReLU -> bf16 (single plane) ----------------

__global__ __launch_bounds__(256) void l0_transform(const float* __restrict__ xa,
                                                    const float* __restrict__ W,
                                                    const float* __restrict__ b,
                                                    const float* __restrict__ gamma,
                                                    const float* __restrict__ beta,
                                                    const float* __restrict__ mean,
                                                    const float* __restrict__ var,
                                                    unsigned short* __restrict__ ohi) {
    int c4 = threadIdx.x & 31;   // feature group: j = c4*4 + i
    int r  = threadIdx.x >> 5;   // node within 8-group
    float w[7][4];
#pragma unroll
    for (int k = 0; k < 7; k++)
#pragma unroll
        for (int i = 0; i < 4; i++) w[k][i] = W[k * HID + c4 * 4 + i];
    float4 bb = ((const float4*)b)[c4];
    float4 ga = ((const float4*)gamma)[c4];
    float4 be = ((const float4*)beta)[c4];
    float4 me = ((const float4*)mean)[c4];
    float4 va = ((const float4*)var)[c4];
    float4 sc;
    sc.x = ga.x * rsqrtf(va.x + BN_EPS);
    sc.y = ga.y * rsqrtf(va.y + BN_EPS);
    sc.z = ga.z * rsqrtf(va.z + BN_EPS);
    sc.w = ga.w * rsqrtf(va.w + BN_EPS);
    __shared__ float s[8][8];
    for (int n0 = blockIdx.x * 8; n0 < NN; n0 += gridDim.x * 8) {
        __syncthreads();
        if (threadIdx.x < 64) s[threadIdx.x >> 3][threadIdx.x & 7] = xa[n0 * 8 + threadIdx.x];
        __syncthreads();
        float o0 = bb.x, o1 = bb.y, o2 = bb.z, o3 = bb.w;
#pragma unroll
        for (int k = 0; k < 7; k++) {
            float xv = s[r][k];
            o0 = fmaf(xv, w[k][0], o0);
            o1 = fmaf(xv, w[k][1], o1);
            o2 = fmaf(xv, w[k][2], o2);
            o3 = fmaf(xv, w[k][3], o3);
        }
        ushort4 hi4;
        hi4.x = f2bf_rn(fmaxf(fmaf(o0 - me.x, sc.x, be.x), 0.f));
        hi4.y = f2bf_rn(fmaxf(fmaf(o1 - me.y, sc.y, be.y), 0.f));
        hi4.z = f2bf_rn(fmaxf(fmaf(o2 - me.z, sc.z, be.z), 0.f));
        hi4.w = f2bf_rn(fmaxf(fmaf(o3 - me.w, sc.w, be.w), 0.f));
        *(ushort4*)(ohi + (size_t)(n0 + r) * HID + c4 * 4) = hi4;
    }
}

// ---------------- layers 1/2 matmul via MFMA ----------------
// v2: persistent blocks (grid 1024) grid-striding over 32-row tiles.
// W hi/lo fragments loaded ONCE into registers; next tile's A fragments
// register-prefetched during compute. A single bf16, W split (fp32-exact W).

__global__ __launch_bounds__(256) void mm_mfma(const unsigned short* __restrict__ A,
                                               const unsigned short* __restrict__ Whi,
                                               const unsigned short* __restrict__ Wlo,
                                               unsigned short* __restrict__ out) {
    int wave = threadIdx.x >> 6;
    int lane = threadIdx.x & 63;
    int mrow = lane & 15;
    int quad = lane >> 4;
    int n0 = wave * 32;

    short8 bh[2][4], bl[2][4];
#pragma unroll
    for (int ct = 0; ct < 2; ct++) {
#pragma unroll
        for (int kc = 0; kc < 4; kc++) {
            size_t off = (size_t)(n0 + ct * 16 + mrow) * HID + kc * 32 + quad * 8;
            bh[ct][kc] = *(const short8*)(Whi + off);
            bl[ct][kc] = *(const short8*)(Wlo + off);
        }
    }

    int tile = blockIdx.x;
    if (tile >= MM_TILES) return;

    short8 ah[2][4];
#pragma unroll
    for (int rt = 0; rt < 2; rt++)
#pragma unroll
        for (int kc = 0; kc < 4; kc++)
            ah[rt][kc] = *(const short8*)(A + (size_t)(tile * 32 + rt * 16 + mrow) * HID + kc * 32 + quad * 8);

    for (;;) {
        int nt = tile + gridDim.x;
        bool has_next = nt < MM_TILES;
        short8 an[2][4];
        if (has_next) {
#pragma unroll
            for (int rt = 0; rt < 2; rt++)
#pragma unroll
                for (int kc = 0; kc < 4; kc++)
                    an[rt][kc] = *(const short8*)(A + (size_t)(nt * 32 + rt * 16 + mrow) * HID + kc * 32 + quad * 8);
        }

        float4v acc[2][2];
#pragma unroll
        for (int rt = 0; rt < 2; rt++)
#pragma unroll
            for (int ct = 0; ct < 2; ct++) {
                acc[rt][ct].x = 0.f; acc[rt][ct].y = 0.f;
                acc[rt][ct].z = 0.f; acc[rt][ct].w = 0.f;
            }

#pragma unroll
        for (int kc = 0; kc < 4; kc++)
#pragma unroll
            for (int rt = 0; rt < 2; rt++)
#pragma unroll
                for (int ct = 0; ct < 2; ct++) {
                    acc[rt][ct] = __builtin_amdgcn_mfma_f32_16x16x32_bf16(ah[rt][kc], bh[ct][kc], acc[rt][ct], 0, 0, 0);
                    acc[rt][ct] = __builtin_amdgcn_mfma_f32_16x16x32_bf16(ah[rt][kc], bl[ct][kc], acc[rt][ct], 0, 0, 0);
                }

        int m0 = tile * 32;
#pragma unroll
        for (int rt = 0; rt < 2; rt++)
#pragma unroll
            for (int ct = 0; ct < 2; ct++) {
                int col = n0 + ct * 16 + mrow;
#pragma unroll
                for (int r = 0; r < 4; r++) {
                    int row = m0 + rt * 16 + quad * 4 + r;
                    out[(size_t)row * HID + col] = f2bf_rn(acc[rt][ct][r]);
                }
            }

        if (!has_next) break;
#pragma unroll
        for (int rt = 0; rt < 2; rt++)
#pragma unroll
            for (int kc = 0; kc < 4; kc++) ah[rt][kc] = an[rt][kc];
        tile = nt;
    }
}

// ---------------- gather-aggregate + self-loop + bias + BN + ReLU ----------------
// v3: 16 lanes/node, 16-B (uint4) gathers, 4x edge unroll. hl bf16 rows (256 B).
// BF16OUT: single bf16 plane (feeds mm); else fp32 (feeds pool).

template <bool BF16OUT>
__global__ __launch_bounds__(256) void gather_bn_t(const unsigned short* __restrict__ hl,
                                                   const int* __restrict__ rs,
                                                   const int* __restrict__ esrc,
                                                   const float* __restrict__ ewt,
                                                   const float* __restrict__ dinv,
                                                   const float* __restrict__ b,
                                                   const float* __restrict__ gamma,
                                                   const float* __restrict__ beta,
                                                   const float* __restrict__ mean,
                                                   const float* __restrict__ var,
                                                   float* __restrict__ outf,
                                                   unsigned short* __restrict__ ohi) {
    int t = blockIdx.x * blockDim.x + threadIdx.x;
    int lane = t & 15;          // 16-B chunk within 256-B row (8 features)
    int n = t >> 4;
    if (n >= NN) return;
    const uint4* hlv = (const uint4*)hl;  // 16 uint4 per row
    float di = dinv[n];
    float dsq = di * di;

    float acc[8], v[8];
    {
        uint4 sv = hlv[(size_t)n * 16 + lane];
        unpack8(sv, v);
        float4 bA = ((const float4*)b)[lane * 2];
        float4 bB = ((const float4*)b)[lane * 2 + 1];
        acc[0] = fmaf(v[0], dsq, bA.x); acc[1] = fmaf(v[1], dsq, bA.y);
        acc[2] = fmaf(v[2], dsq, bA.z); acc[3] = fmaf(v[3], dsq, bA.w);
        acc[4] = fmaf(v[4], dsq, bB.x); acc[5] = fmaf(v[5], dsq, bB.y);
        acc[6] = fmaf(v[6], dsq, bB.z); acc[7] = fmaf(v[7], dsq, bB.w);
    }

    int e0 = rs[n], e1 = rs[n + 1];
    int e = e0;
    for (; e + 3 < e1; e += 4) {
        int s0 = esrc[e], s1 = esrc[e + 1], s2 = esrc[e + 2], s3 = esrc[e + 3];
        float w0 = ewt[e], w1 = ewt[e + 1], w2 = ewt[e + 2], w3 = ewt[e + 3];
        uint4 u0 = hlv[(size_t)s0 * 16 + lane];
        uint4 u1 = hlv[(size_t)s1 * 16 + lane];
        uint4 u2 = hlv[(size_t)s2 * 16 + lane];
        uint4 u3 = hlv[(size_t)s3 * 16 + lane];
        unpack8(u0, v);
#pragma unroll
        for (int i = 0; i < 8; i++) acc[i] = fmaf(v[i], w0, acc[i]);
        unpack8(u1, v);
#pragma unroll
        for (int i = 0; i < 8; i++) acc[i] = fmaf(v[i], w1, acc[i]);
        unpack8(u2, v);
#pragma unroll
        for (int i = 0; i < 8; i++) acc[i] = fmaf(v[i], w2, acc[i]);
        unpack8(u3, v);
#pragma unroll
        for (int i = 0; i < 8; i++) acc[i] = fmaf(v[i], w3, acc[i]);
    }
    for (; e < e1; e++) {
        int s0 = esrc[e];
        float w0 = ewt[e];
        uint4 u0 = hlv[(size_t)s0 * 16 + lane];
        unpack8(u0, v);
#pragma unroll
        for (int i = 0; i < 8; i++) acc[i] = fmaf(v[i], w0, acc[i]);
    }

    float4 gA = ((const float4*)gamma)[lane * 2], gB = ((const float4*)gamma)[lane * 2 + 1];
    float4 eA = ((const float4*)beta)[lane * 2],  eB = ((const float4*)beta)[lane * 2 + 1];
    float4 mA = ((const float4*)mean)[lane * 2],  mB = ((const float4*)mean)[lane * 2 + 1];
    float4 vA = ((const float4*)var)[lane * 2],   vB = ((const float4*)var)[lane * 2 + 1];
    float o[8];
    o[0] = fmaxf(fmaf(acc[0] - mA.x, gA.x * rsqrtf(vA.x + BN_EPS), eA.x), 0.f);
    o[1] = fmaxf(fmaf(acc[1] - mA.y, gA.y * rsqrtf(vA.y + BN_EPS), eA.y), 0.f);
    o[2] = fmaxf(fmaf(acc[2] - mA.z, gA.z * rsqrtf(vA.z + BN_EPS), eA.z), 0.f);
    o[3] = fmaxf(fmaf(acc[3] - mA.w, gA.w * rsqrtf(vA.w + BN_EPS), eA.w), 0.f);
    o[4] = fmaxf(fmaf(acc[4] - mB.x, gB.x * rsqrtf(vB.x + BN_EPS), eB.x), 0.f);
    o[5] = fmaxf(fmaf(acc[5] - mB.y, gB.y * rsqrtf(vB.y + BN_EPS), eB.y), 0.f);
    o[6] = fmaxf(fmaf(acc[6] - mB.z, gB.z * rsqrtf(vB.z + BN_EPS), eB.z), 0.f);
    o[7] = fmaxf(fmaf(acc[7] - mB.w, gB.w * rsqrtf(vB.w + BN_EPS), eB.w), 0.f);

    if (BF16OUT) {
        uint4 p;
        p.x = (unsigned)f2bf_rn(o[0]) | ((unsigned)f2bf_rn(o[1]) << 16);
        p.y = (unsigned)f2bf_rn(o[2]) | ((unsigned)f2bf_rn(o[3]) << 16);
        p.z = (unsigned)f2bf_rn(o[4]) | ((unsigned)f2bf_rn(o[5]) << 16);
        p.w = (unsigned)f2bf_rn(o[6]) | ((unsigned)f2bf_rn(o[7]) << 16);
        ((uint4*)ohi)[(size_t)n * 16 + lane] = p;
    } else {
        ((float4*)outf)[(size_t)n * 32 + lane * 2]     = make_float4(o[0], o[1], o[2], o[3]);
        ((float4*)outf)[(size_t)n * 32 + lane * 2 + 1] = make_float4(o[4], o[5], o[6], o[7]);
    }
}

// ---------------- fused global mean pool + classifier ----------------

__global__ __launch_bounds__(1024) void poolcls_kernel(const float* __restrict__ h,
                                                       const int* __restrict__ batch,
                                                       const float* __restrict__ pv,
                                                       const float* __restrict__ cw1,
                                                       const float* __restrict__ cb1,
                                                       const float* __restrict__ cw2,
                                                       const float* __restrict__ cb2,
                                                       float* __restrict__ out) {
    int g = blockIdx.x;
    int lane = threadIdx.x & 31;   // float4 index within feature row
    int row = threadIdx.x >> 5;    // 0..31
    __shared__ int se[2];
    __shared__ float emb[192];
    __shared__ float hid[96];
    if (threadIdx.x < 2) {
        int target = g + threadIdx.x;
        int lo = 0, hi = NN;
        while (lo < hi) {
            int mid = (lo + hi) >> 1;
            if (batch[mid] < target) lo = mid + 1; else hi = mid;
        }
        se[threadIdx.x] = lo;
    }
    if (threadIdx.x < 64) emb[128 + threadIdx.x] = pv[threadIdx.x];
    __syncthreads();
    int start = se[0], end = se[1];
    const float4* h4 = (const float4*)h;
    float4 acc = make_float4(0.f, 0.f, 0.f, 0.f);
    for (int n = start + row; n < end; n += 32) {
        float4 v = h4[(size_t)n * 32 + lane];
        acc.x += v.x; acc.y += v.y; acc.z += v.z; acc.w += v.w;
    }
    __shared__ float4 part[32][32];
    part[row][lane] = acc;
    __syncthreads();
#pragma unroll
    for (int off = 16; off >= 1; off >>= 1) {
        if (row < off) {
            float4 a = part[row][lane];
            float4 c = part[row + off][lane];
            a.x += c.x; a.y += c.y; a.z += c.z; a.w += c.w;
            part[row][lane] = a;
        }
        __syncthreads();
    }
    if (row == 0) {
        float inv = 1.0f / fmaxf((float)(end - start), 1.0f);
        float4 a = part[0][lane];
        a.x *= inv; a.y *= inv; a.z *= inv; a.w *= inv;
        ((float4*)emb)[lane] = a;
    }
    __syncthreads();
    int j = threadIdx.x;
    if (j < 96) {
        float a = cb1[j];
        for (int k = 0; k < 192; k++) a = fmaf(emb[k], cw1[k * 96 + j], a);
        hid[j] = fmaxf(a, 0.f) * cw2[j];
    }
    __syncthreads();
    if (j == 0) {
        float s = cb2[0];
        for (int k = 0; k < 96; k++) s += hid[k];
        out[g] = s;
    }
}

extern "C" void kernel_launch(void* const* d_in, const int* in_sizes, int n_in,
                              void* d_out, int out_size, void* d_ws, size_t ws_size,
                              hipStream_t stream) {
    const float* x        = (const float*)d_in[0];
    const int*   eidx     = (const int*)d_in[1];
    const int*   batch    = (const int*)d_in[2];
    const float* pocket   = (const float*)d_in[3];
    const float* W0 = (const float*)d_in[4];
    const float* b0 = (const float*)d_in[5];
    const float* W1 = (const float*)d_in[6];
    const float* b1 = (const float*)d_in[7];
    const float* W2 = (const float*)d_in[8];
    const float* b2 = (const float*)d_in[9];
    const float* bn_gamma = (const float*)d_in[10];
    const float* bn_beta  = (const float*)d_in[11];
    const float* bn_mean  = (const float*)d_in[12];
    const float* bn_var   = (const float*)d_in[13];
    const float* pw1 = (const float*)d_in[14]; const float* pb1 = (const float*)d_in[15];
    const float* pw2 = (const float*)d_in[16]; const float* pb2 = (const float*)d_in[17];
    const float* cw1 = (const float*)d_in[18]; const float* cb1 = (const float*)d_in[19];
    const float* cw2 = (const float*)d_in[20]; const float* cb2 = (const float*)d_in[21];
    float* out = (float*)d_out;

    // Workspace layout (4-byte units):
    float* ws   = (float*)d_ws;
    float* dinv = ws;                                   // NN
    int*   cnt  = (int*)(ws + NN);                      // NN (hist, then cursor)
    int*   rs   = cnt + NN;                             // NN+1
    int*   tsum = rs + NN + 1;                          // 128
    int*   esrc = tsum + 128;                           // NE
    float* ewt  = (float*)(esrc + NE);                  // NE
    float* xa   = ewt + NE;                             // NN*8
    unsigned short* w1hi = (unsigned short*)(xa + (size_t)NN * 8);  // 16384 each
    unsigned short* w1lo = w1hi + HID * HID;
    unsigned short* w2hi = w1lo + HID * HID;
    unsigned short* w2lo = w2hi + HID * HID;
    size_t head = (size_t)NN * 2 + (NN + 1) + 128 + (size_t)NE * 2 + (size_t)NN * 8
                + (4 * HID * HID) / 2;                  // 4 ushort arrays = 2*HID*HID floats
    head = (head + 3) & ~(size_t)3;                     // 16B align
    // R1 region (NN*HID floats): holds bf16 A plane during layers 1/2;
    // final gather writes fp32 Cf over the same bytes (A no longer needed).
    float* R1   = ws + head;
    unsigned short* A = (unsigned short*)R1;            // NN*HID ushort (bf16 act)
    float* Cf   = R1;                                   // NN*HID float (aliases A)
    unsigned short* B = (unsigned short*)(R1 + (size_t)NN * HID);  // NN*HID ushort (bf16 hl)
    float* pv   = R1 + (size_t)NN * HID + (size_t)NN * HID / 2;    // 64

    const int* srcp = eidx;
    const int* dstp = eidx + NE;

    // ---- build CSR (by dst) + dinv + edge weights; split W1/W2 + pocket ----
    hipMemsetAsync(cnt, 0, NN * sizeof(int), stream);
    hist_kernel<<<(NE + 255) / 256, 256, 0, stream>>>(dstp, cnt);
    scan_a<<<NTILES, 256, 0, stream>>>(cnt, rs, tsum, dinv);
    scan_b<<<1, 128, 0, stream>>>(tsum);
    scan_c<<<NTILES, 256, 0, stream>>>(rs, tsum, cnt);  // cnt becomes cursor
    bucket_kernel<<<(NE + 255) / 256, 256, 0, stream>>>(srcp, dstp, dinv, cnt, esrc, ewt);
    prep_kernel<<<65, 256, 0, stream>>>(W1, W2, w1hi, w1lo, w2hi, w2lo,
                                        pocket, pw1, pb1, pw2, pb2, pv);

    // ---- layer 0: aggregate x, then transform -> bf16 plane A ----
    xagg_kernel<<<(NN * 8 + 255) / 256, 256, 0, stream>>>(x, rs, esrc, ewt, dinv, xa);
    l0_transform<<<2048, 256, 0, stream>>>(xa, W0, b0,
                                           bn_gamma + 0 * HID, bn_beta + 0 * HID,
                                           bn_mean + 0 * HID, bn_var + 0 * HID, A);

    const int MM_BLOCKS = 1024;          // persistent, ~3 tiles/block
    const int GA_BLOCKS = (NN * 16 + 255) / 256;

    // ---- layer 1 ----
    mm_mfma<<<MM_BLOCKS, 256, 0, stream>>>(A, w1hi, w1lo, B);
    gather_bn_t<true><<<GA_BLOCKS, 256, 0, stream>>>(
        B, rs, esrc, ewt, dinv, b1,
        bn_gamma + 1 * HID, bn_beta + 1 * HID, bn_mean + 1 * HID, bn_var + 1 * HID,
        nullptr, A);
    // ---- layer 2 ----
    mm_mfma<<<MM_BLOCKS, 256, 0, stream>>>(A, w2hi, w2lo, B);
    gather_bn_t<false><<<GA_BLOCKS, 256, 0, stream>>>(
        B, rs, esrc, ewt, dinv, b2,
        bn_gamma + 2 * HID, bn_beta + 2 * HID, bn_mean + 2 * HID, bn_var + 2 * HID,
        Cf, nullptr);

    // fused pool + classifier
    poolcls_kernel<<<NG, 1024, 0, stream>>>(Cf, batch, pv, cw1, cb1, cw2, cb2, out);
}

// Round 13
// 340.699 us; speedup vs baseline: 1.3927x; 1.0054x over previous
//
#include <hip/hip_runtime.h>

// Problem constants (match reference setup_inputs)
#define NN 100000
#define NE 600000
#define NG 256
#define HID 128
#define BN_EPS 1e-5f

#define SCAN_TILE 1024
#define NTILES ((NN + SCAN_TILE - 1) / SCAN_TILE)  // 98
#define MM_TILES (NN / 32)                          // 3125 (NN % 32 == 0)

typedef __attribute__((ext_vector_type(8))) short short8;
typedef __attribute__((ext_vector_type(4))) float float4v;

// bf16 round-to-nearest-even helpers
__device__ __forceinline__ unsigned short f2bf_rn(float f) {
    unsigned u = __float_as_uint(f);
    unsigned r = u + 0x7FFFu + ((u >> 16) & 1u);
    return (unsigned short)(r >> 16);
}
__device__ __forceinline__ float bf2f(unsigned short h) {
    return __uint_as_float((unsigned)h << 16);
}
__device__ __forceinline__ void unpack8(uint4 u, float* f) {
    f[0] = __uint_as_float(u.x << 16); f[1] = __uint_as_float(u.x & 0xFFFF0000u);
    f[2] = __uint_as_float(u.y << 16); f[3] = __uint_as_float(u.y & 0xFFFF0000u);
    f[4] = __uint_as_float(u.z << 16); f[5] = __uint_as_float(u.z & 0xFFFF0000u);
    f[6] = __uint_as_float(u.w << 16); f[7] = __uint_as_float(u.w & 0xFFFF0000u);
}

// ---------------- histogram of dst (in-degree) ----------------

__global__ __launch_bounds__(256) void hist_kernel(const int* __restrict__ dst, int* __restrict__ cnt) {
    int e = blockIdx.x * blockDim.x + threadIdx.x;
    if (e < NE) atomicAdd(&cnt[dst[e]], 1);
}

// ---------------- 2-level exclusive scan of cnt -> row_start (+ dinv fused) ----------------

__global__ __launch_bounds__(256) void scan_a(const int* __restrict__ cnt, int* __restrict__ rs,
                                              int* __restrict__ tsum, float* __restrict__ dinv) {
    __shared__ int s[256];
    int t = threadIdx.x;
    int base = blockIdx.x * SCAN_TILE;
    int idx = base + t * 4;
    int v0 = (idx + 0 < NN) ? cnt[idx + 0] : 0;
    int v1 = (idx + 1 < NN) ? cnt[idx + 1] : 0;
    int v2 = (idx + 2 < NN) ? cnt[idx + 2] : 0;
    int v3 = (idx + 3 < NN) ? cnt[idx + 3] : 0;
    if (idx + 0 < NN) dinv[idx + 0] = rsqrtf((float)v0 + 1.0f);
    if (idx + 1 < NN) dinv[idx + 1] = rsqrtf((float)v1 + 1.0f);
    if (idx + 2 < NN) dinv[idx + 2] = rsqrtf((float)v2 + 1.0f);
    if (idx + 3 < NN) dinv[idx + 3] = rsqrtf((float)v3 + 1.0f);
    int local = v0 + v1 + v2 + v3;
    s[t] = local;
    __syncthreads();
    for (int off = 1; off < 256; off <<= 1) {
        int x = (t >= off) ? s[t - off] : 0;
        __syncthreads();
        s[t] += x;
        __syncthreads();
    }
    int pre = s[t] - local;  // exclusive prefix within tile
    if (t == 255) tsum[blockIdx.x] = s[255];
    if (idx + 0 < NN) rs[idx + 0] = pre; pre += v0;
    if (idx + 1 < NN) rs[idx + 1] = pre; pre += v1;
    if (idx + 2 < NN) rs[idx + 2] = pre; pre += v2;
    if (idx + 3 < NN) rs[idx + 3] = pre;
}

__global__ __launch_bounds__(128) void scan_b(int* __restrict__ tsum) {
    __shared__ int s[128];
    int t = threadIdx.x;
    int v = (t < NTILES) ? tsum[t] : 0;
    s[t] = v;
    __syncthreads();
    for (int off = 1; off < 128; off <<= 1) {
        int x = (t >= off) ? s[t - off] : 0;
        __syncthreads();
        s[t] += x;
        __syncthreads();
    }
    if (t < NTILES) tsum[t] = s[t] - v;  // exclusive
}

__global__ __launch_bounds__(256) void scan_c(int* __restrict__ rs, const int* __restrict__ tsum,
                                              int* __restrict__ cursor) {
    int t = threadIdx.x;
    int base = blockIdx.x * SCAN_TILE;
    int off = tsum[blockIdx.x];
    for (int k = 0; k < 4; k++) {
        int idx = base + t * 4 + k;
        if (idx < NN) {
            int v = rs[idx] + off;
            rs[idx] = v;
            cursor[idx] = v;
        }
    }
    if (blockIdx.x == 0 && t == 0) rs[NN] = NE;
}

// ---------------- bucket edges by dst (esrc only; weights computed on the fly) ----------------

__global__ __launch_bounds__(256) void bucket_kernel(const int* __restrict__ src, const int* __restrict__ dst,
                                                     int* __restrict__ cursor, int* __restrict__ esrc) {
    int e = blockIdx.x * blockDim.x + threadIdx.x;
    if (e < NE) {
        int pos = atomicAdd(&cursor[dst[e]], 1);
        esrc[pos] = src[e];
    }
}

// ---------------- prep: split W1/W2 (transposed) + pocket MLP ----------------

__global__ __launch_bounds__(256) void prep_kernel(const float* __restrict__ W1, const float* __restrict__ W2,
                                                   unsigned short* __restrict__ w1hi, unsigned short* __restrict__ w1lo,
                                                   unsigned short* __restrict__ w2hi, unsigned short* __restrict__ w2lo,
                                                   const float* __restrict__ pocket,
                                                   const float* __restrict__ pw1, const float* __restrict__ pb1,
                                                   const float* __restrict__ pw2, const float* __restrict__ pb2,
                                                   float* __restrict__ pv) {
    if (blockIdx.x < 64) {
        int t = blockIdx.x * 256 + threadIdx.x;
        int k = t >> 7, n = t & 127;      // W[k][n]
        int to = n * HID + k;             // Wt[n][k]
        float v1 = W1[t];
        unsigned short h1 = f2bf_rn(v1);
        w1hi[to] = h1;
        w1lo[to] = f2bf_rn(v1 - bf2f(h1));
        float v2 = W2[t];
        unsigned short h2 = f2bf_rn(v2);
        w2hi[to] = h2;
        w2lo[to] = f2bf_rn(v2 - bf2f(h2));
    } else {
        __shared__ float t1[64];
        int j = threadIdx.x;
        if (j < 64) {
            float acc = pb1[j];
            for (int k = 0; k < 28; k++) acc = fmaf(pocket[k], pw1[k * 64 + j], acc);
            t1[j] = fmaxf(acc, 0.f);
        }
        __syncthreads();
        if (j < 64) {
            float acc2 = pb2[j];
            for (int k = 0; k < 64; k++) acc2 = fmaf(t1[k], pw2[k * 64 + j], acc2);
            pv[j] = acc2;
        }
    }
}

// ---------------- layer 0 part A: aggregate raw x (7-dim) -> xa [NN,8] ----------------

__global__ __launch_bounds__(256) void xagg_kernel(const float* __restrict__ x,
                                                   const int* __restrict__ rs,
                                                   const int* __restrict__ esrc,
                                                   const float* __restrict__ dinv,
                                                   float* __restrict__ xa) {
    int t = blockIdx.x * blockDim.x + threadIdx.x;
    int f = t & 7;
    int n = t >> 3;
    if (n >= NN) return;
    float acc = 0.f;
    if (f < 7) {
        float di = dinv[n];
        acc = x[n * 7 + f] * di * di;
        int e0 = rs[n], e1 = rs[n + 1];
        int e = e0;
        for (; e + 1 < e1; e += 2) {
            int s0 = esrc[e], s1 = esrc[e + 1];
            float w0 = dinv[s0] * di, w1 = dinv[s1] * di;
            float a0 = x[s0 * 7 + f];
            float a1 = x[s1 * 7 + f];
            acc = fmaf(a0, w0, acc);
            acc = fmaf(a1, w1, acc);
        }
        if (e < e1) {
            int s0 = esrc[e];
            acc = fmaf(x[s0 * 7 + f], dinv[s0] * di, acc);
        }
    }
    xa[n * 8 + f] = acc;
}

// ---------------- layer 0 part B: xa @ W0 + b -> BN -> ReLU -> bf16 (single plane) ----------------

__global__ __launch_bounds__(256) void l0_transform(const float* __restrict__ xa,
                                                    const float* __restrict__ W,
                                                    const float* __restrict__ b,
                                                    const float* __restrict__ gamma,
                                                    const float* __restrict__ beta,
                                                    const float* __restrict__ mean,
                                                    const float* __restrict__ var,
                                                    unsigned short* __restrict__ ohi) {
    int c4 = threadIdx.x & 31;   // feature group: j = c4*4 + i
    int r  = threadIdx.x >> 5;   // node within 8-group
    float w[7][4];
#pragma unroll
    for (int k = 0; k < 7; k++)
#pragma unroll
        for (int i = 0; i < 4; i++) w[k][i] = W[k * HID + c4 * 4 + i];
    float4 bb = ((const float4*)b)[c4];
    float4 ga = ((const float4*)gamma)[c4];
    float4 be = ((const float4*)beta)[c4];
    float4 me = ((const float4*)mean)[c4];
    float4 va = ((const float4*)var)[c4];
    float4 sc;
    sc.x = ga.x * rsqrtf(va.x + BN_EPS);
    sc.y = ga.y * rsqrtf(va.y + BN_EPS);
    sc.z = ga.z * rsqrtf(va.z + BN_EPS);
    sc.w = ga.w * rsqrtf(va.w + BN_EPS);
    __shared__ float s[8][8];
    for (int n0 = blockIdx.x * 8; n0 < NN; n0 += gridDim.x * 8) {
        __syncthreads();
        if (threadIdx.x < 64) s[threadIdx.x >> 3][threadIdx.x & 7] = xa[n0 * 8 + threadIdx.x];
        __syncthreads();
        float o0 = bb.x, o1 = bb.y, o2 = bb.z, o3 = bb.w;
#pragma unroll
        for (int k = 0; k < 7; k++) {
            float xv = s[r][k];
            o0 = fmaf(xv, w[k][0], o0);
            o1 = fmaf(xv, w[k][1], o1);
            o2 = fmaf(xv, w[k][2], o2);
            o3 = fmaf(xv, w[k][3], o3);
        }
        ushort4 hi4;
        hi4.x = f2bf_rn(fmaxf(fmaf(o0 - me.x, sc.x, be.x), 0.f));
        hi4.y = f2bf_rn(fmaxf(fmaf(o1 - me.y, sc.y, be.y), 0.f));
        hi4.z = f2bf_rn(fmaxf(fmaf(o2 - me.z, sc.z, be.z), 0.f));
        hi4.w = f2bf_rn(fmaxf(fmaf(o3 - me.w, sc.w, be.w), 0.f));
        *(ushort4*)(ohi + (size_t)(n0 + r) * HID + c4 * 4) = hi4;
    }
}

// ---------------- layers 1/2 matmul via MFMA ----------------
// Persistent blocks; W hi/lo fragments register-resident; A prefetched.

__global__ __launch_bounds__(256) void mm_mfma(const unsigned short* __restrict__ A,
                                               const unsigned short* __restrict__ Whi,
                                               const unsigned short* __restrict__ Wlo,
                                               unsigned short* __restrict__ out) {
    int wave = threadIdx.x >> 6;
    int lane = threadIdx.x & 63;
    int mrow = lane & 15;
    int quad = lane >> 4;
    int n0 = wave * 32;

    short8 bh[2][4], bl[2][4];
#pragma unroll
    for (int ct = 0; ct < 2; ct++) {
#pragma unroll
        for (int kc = 0; kc < 4; kc++) {
            size_t off = (size_t)(n0 + ct * 16 + mrow) * HID + kc * 32 + quad * 8;
            bh[ct][kc] = *(const short8*)(Whi + off);
            bl[ct][kc] = *(const short8*)(Wlo + off);
        }
    }

    int tile = blockIdx.x;
    if (tile >= MM_TILES) return;

    short8 ah[2][4];
#pragma unroll
    for (int rt = 0; rt < 2; rt++)
#pragma unroll
        for (int kc = 0; kc < 4; kc++)
            ah[rt][kc] = *(const short8*)(A + (size_t)(tile * 32 + rt * 16 + mrow) * HID + kc * 32 + quad * 8);

    for (;;) {
        int nt = tile + gridDim.x;
        bool has_next = nt < MM_TILES;
        short8 an[2][4];
        if (has_next) {
#pragma unroll
            for (int rt = 0; rt < 2; rt++)
#pragma unroll
                for (int kc = 0; kc < 4; kc++)
                    an[rt][kc] = *(const short8*)(A + (size_t)(nt * 32 + rt * 16 + mrow) * HID + kc * 32 + quad * 8);
        }

        float4v acc[2][2];
#pragma unroll
        for (int rt = 0; rt < 2; rt++)
#pragma unroll
            for (int ct = 0; ct < 2; ct++) {
                acc[rt][ct].x = 0.f; acc[rt][ct].y = 0.f;
                acc[rt][ct].z = 0.f; acc[rt][ct].w = 0.f;
            }

#pragma unroll
        for (int kc = 0; kc < 4; kc++)
#pragma unroll
            for (int rt = 0; rt < 2; rt++)
#pragma unroll
                for (int ct = 0; ct < 2; ct++) {
                    acc[rt][ct] = __builtin_amdgcn_mfma_f32_16x16x32_bf16(ah[rt][kc], bh[ct][kc], acc[rt][ct], 0, 0, 0);
                    acc[rt][ct] = __builtin_amdgcn_mfma_f32_16x16x32_bf16(ah[rt][kc], bl[ct][kc], acc[rt][ct], 0, 0, 0);
                }

        int m0 = tile * 32;
#pragma unroll
        for (int rt = 0; rt < 2; rt++)
#pragma unroll
            for (int ct = 0; ct < 2; ct++) {
                int col = n0 + ct * 16 + mrow;
#pragma unroll
                for (int r = 0; r < 4; r++) {
                    int row = m0 + rt * 16 + quad * 4 + r;
                    out[(size_t)row * HID + col] = f2bf_rn(acc[rt][ct][r]);
                }
            }

        if (!has_next) break;
#pragma unroll
        for (int rt = 0; rt < 2; rt++)
#pragma unroll
            for (int kc = 0; kc < 4; kc++) ah[rt][kc] = an[rt][kc];
        tile = nt;
    }
}

// ---------------- gather-aggregate + self-loop + bias + BN + ReLU -> bf16 ----------------
// 16 lanes/node, uint4 gathers, 4x unroll; weights dinv[s]*dinv[n] on the fly
// (dinv is 400 KB, L2-resident; same addr across the 16 lanes -> broadcast).

__global__ __launch_bounds__(256) void gather_bn(const unsigned short* __restrict__ hl,
                                                 const int* __restrict__ rs,
                                                 const int* __restrict__ esrc,
                                                 const float* __restrict__ dinv,
                                                 const float* __restrict__ b,
                                                 const float* __restrict__ gamma,
                                                 const float* __restrict__ beta,
                                                 const float* __restrict__ mean,
                                                 const float* __restrict__ var,
                                                 unsigned short* __restrict__ ohi) {
    int t = blockIdx.x * blockDim.x + threadIdx.x;
    int lane = t & 15;          // 16-B chunk within 256-B row (8 features)
    int n = t >> 4;
    if (n >= NN) return;
    const uint4* hlv = (const uint4*)hl;  // 16 uint4 per row
    float di = dinv[n];
    float dsq = di * di;

    float acc[8], v[8];
    {
        uint4 sv = hlv[(size_t)n * 16 + lane];
        unpack8(sv, v);
        float4 bA = ((const float4*)b)[lane * 2];
        float4 bB = ((const float4*)b)[lane * 2 + 1];
        acc[0] = fmaf(v[0], dsq, bA.x); acc[1] = fmaf(v[1], dsq, bA.y);
        acc[2] = fmaf(v[2], dsq, bA.z); acc[3] = fmaf(v[3], dsq, bA.w);
        acc[4] = fmaf(v[4], dsq, bB.x); acc[5] = fmaf(v[5], dsq, bB.y);
        acc[6] = fmaf(v[6], dsq, bB.z); acc[7] = fmaf(v[7], dsq, bB.w);
    }

    int e0 = rs[n], e1 = rs[n + 1];
    int e = e0;
    for (; e + 3 < e1; e += 4) {
        int s0 = esrc[e], s1 = esrc[e + 1], s2 = esrc[e + 2], s3 = esrc[e + 3];
        float w0 = dinv[s0] * di, w1 = dinv[s1] * di;
        float w2 = dinv[s2] * di, w3 = dinv[s3] * di;
        uint4 u0 = hlv[(size_t)s0 * 16 + lane];
        uint4 u1 = hlv[(size_t)s1 * 16 + lane];
        uint4 u2 = hlv[(size_t)s2 * 16 + lane];
        uint4 u3 = hlv[(size_t)s3 * 16 + lane];
        unpack8(u0, v);
#pragma unroll
        for (int i = 0; i < 8; i++) acc[i] = fmaf(v[i], w0, acc[i]);
        unpack8(u1, v);
#pragma unroll
        for (int i = 0; i < 8; i++) acc[i] = fmaf(v[i], w1, acc[i]);
        unpack8(u2, v);
#pragma unroll
        for (int i = 0; i < 8; i++) acc[i] = fmaf(v[i], w2, acc[i]);
        unpack8(u3, v);
#pragma unroll
        for (int i = 0; i < 8; i++) acc[i] = fmaf(v[i], w3, acc[i]);
    }
    for (; e < e1; e++) {
        int s0 = esrc[e];
        float w0 = dinv[s0] * di;
        uint4 u0 = hlv[(size_t)s0 * 16 + lane];
        unpack8(u0, v);
#pragma unroll
        for (int i = 0; i < 8; i++) acc[i] = fmaf(v[i], w0, acc[i]);
    }

    float4 gA = ((const float4*)gamma)[lane * 2], gB = ((const float4*)gamma)[lane * 2 + 1];
    float4 eA = ((const float4*)beta)[lane * 2],  eB = ((const float4*)beta)[lane * 2 + 1];
    float4 mA = ((const float4*)mean)[lane * 2],  mB = ((const float4*)mean)[lane * 2 + 1];
    float4 vA = ((const float4*)var)[lane * 2],   vB = ((const float4*)var)[lane * 2 + 1];
    float o[8];
    o[0] = fmaxf(fmaf(acc[0] - mA.x, gA.x * rsqrtf(vA.x + BN_EPS), eA.x), 0.f);
    o[1] = fmaxf(fmaf(acc[1] - mA.y, gA.y * rsqrtf(vA.y + BN_EPS), eA.y), 0.f);
    o[2] = fmaxf(fmaf(acc[2] - mA.z, gA.z * rsqrtf(vA.z + BN_EPS), eA.z), 0.f);
    o[3] = fmaxf(fmaf(acc[3] - mA.w, gA.w * rsqrtf(vA.w + BN_EPS), eA.w), 0.f);
    o[4] = fmaxf(fmaf(acc[4] - mB.x, gB.x * rsqrtf(vB.x + BN_EPS), eB.x), 0.f);
    o[5] = fmaxf(fmaf(acc[5] - mB.y, gB.y * rsqrtf(vB.y + BN_EPS), eB.y), 0.f);
    o[6] = fmaxf(fmaf(acc[6] - mB.z, gB.z * rsqrtf(vB.z + BN_EPS), eB.z), 0.f);
    o[7] = fmaxf(fmaf(acc[7] - mB.w, gB.w * rsqrtf(vB.w + BN_EPS), eB.w), 0.f);

    uint4 p;
    p.x = (unsigned)f2bf_rn(o[0]) | ((unsigned)f2bf_rn(o[1]) << 16);
    p.y = (unsigned)f2bf_rn(o[2]) | ((unsigned)f2bf_rn(o[3]) << 16);
    p.z = (unsigned)f2bf_rn(o[4]) | ((unsigned)f2bf_rn(o[5]) << 16);
    p.w = (unsigned)f2bf_rn(o[6]) | ((unsigned)f2bf_rn(o[7]) << 16);
    ((uint4*)ohi)[(size_t)n * 16 + lane] = p;
}

// ---------------- fused global mean pool + classifier (bf16 input) ----------------

__global__ __launch_bounds__(1024) void poolcls_kernel(const unsigned short* __restrict__ h,
                                                       const int* __restrict__ batch,
                                                       const float* __restrict__ pv,
                                                       const float* __restrict__ cw1,
                                                       const float* __restrict__ cb1,
                                                       const float* __restrict__ cw2,
                                                       const float* __restrict__ cb2,
                                                       float* __restrict__ out) {
    int g = blockIdx.x;
    int lane = threadIdx.x & 31;   // 8-B chunk (4 features) within 256-B row
    int row = threadIdx.x >> 5;    // 0..31
    __shared__ int se[2];
    __shared__ float emb[192];
    __shared__ float hid[96];
    if (threadIdx.x < 2) {
        int target = g + threadIdx.x;
        int lo = 0, hi = NN;
        while (lo < hi) {
            int mid = (lo + hi) >> 1;
            if (batch[mid] < target) lo = mid + 1; else hi = mid;
        }
        se[threadIdx.x] = lo;
    }
    if (threadIdx.x < 64) emb[128 + threadIdx.x] = pv[threadIdx.x];
    __syncthreads();
    int start = se[0], end = se[1];
    const uint2* h2 = (const uint2*)h;  // 32 uint2 per row
    float4 acc = make_float4(0.f, 0.f, 0.f, 0.f);
    for (int n = start + row; n < end; n += 32) {
        uint2 u = h2[(size_t)n * 32 + lane];
        acc.x += __uint_as_float(u.x << 16);
        acc.y += __uint_as_float(u.x & 0xFFFF0000u);
        acc.z += __uint_as_float(u.y << 16);
        acc.w += __uint_as_float(u.y & 0xFFFF0000u);
    }
    __shared__ float4 part[32][32];
    part[row][lane] = acc;
    __syncthreads();
#pragma unroll
    for (int off = 16; off >= 1; off >>= 1) {
        if (row < off) {
            float4 a = part[row][lane];
            float4 c = part[row + off][lane];
            a.x += c.x; a.y += c.y; a.z += c.z; a.w += c.w;
            part[row][lane] = a;
        }
        __syncthreads();
    }
    if (row == 0) {
        float inv = 1.0f / fmaxf((float)(end - start), 1.0f);
        float4 a = part[0][lane];
        a.x *= inv; a.y *= inv; a.z *= inv; a.w *= inv;
        ((float4*)emb)[lane] = a;
    }
    __syncthreads();
    int j = threadIdx.x;
    if (j < 96) {
        float a = cb1[j];
        for (int k = 0; k < 192; k++) a = fmaf(emb[k], cw1[k * 96 + j], a);
        hid[j] = fmaxf(a, 0.f) * cw2[j];
    }
    __syncthreads();
    if (j == 0) {
        float s = cb2[0];
        for (int k = 0; k < 96; k++) s += hid[k];
        out[g] = s;
    }
}

extern "C" void kernel_launch(void* const* d_in, const int* in_sizes, int n_in,
                              void* d_out, int out_size, void* d_ws, size_t ws_size,
                              hipStream_t stream) {
    const float* x        = (const float*)d_in[0];
    const int*   eidx     = (const int*)d_in[1];
    const int*   batch    = (const int*)d_in[2];
    const float* pocket   = (const float*)d_in[3];
    const float* W0 = (const float*)d_in[4];
    const float* b0 = (const float*)d_in[5];
    const float* W1 = (const float*)d_in[6];
    const float* b1 = (const float*)d_in[7];
    const float* W2 = (const float*)d_in[8];
    const float* b2 = (const float*)d_in[9];
    const float* bn_gamma = (const float*)d_in[10];
    const float* bn_beta  = (const float*)d_in[11];
    const float* bn_mean  = (const float*)d_in[12];
    const float* bn_var   = (const float*)d_in[13];
    const float* pw1 = (const float*)d_in[14]; const float* pb1 = (const float*)d_in[15];
    const float* pw2 = (const float*)d_in[16]; const float* pb2 = (const float*)d_in[17];
    const float* cw1 = (const float*)d_in[18]; const float* cb1 = (const float*)d_in[19];
    const float* cw2 = (const float*)d_in[20]; const float* cb2 = (const float*)d_in[21];
    float* out = (float*)d_out;

    // Workspace layout (4-byte units):
    float* ws   = (float*)d_ws;
    float* dinv = ws;                                   // NN
    int*   cnt  = (int*)(ws + NN);                      // NN (hist, then cursor)
    int*   rs   = cnt + NN;                             // NN+1
    int*   tsum = rs + NN + 1;                          // 128
    int*   esrc = tsum + 128;                           // NE
    float* xa   = (float*)(esrc + NE);                  // NN*8
    unsigned short* w1hi = (unsigned short*)(xa + (size_t)NN * 8);  // 16384 each
    unsigned short* w1lo = w1hi + HID * HID;
    unsigned short* w2hi = w1lo + HID * HID;
    unsigned short* w2lo = w2hi + HID * HID;
    size_t head = (size_t)NN * 2 + (NN + 1) + 128 + NE + (size_t)NN * 8
                + (4 * HID * HID) / 2;
    head = (head + 3) & ~(size_t)3;                     // 16B align
    unsigned short* A = (unsigned short*)(ws + head);   // NN*HID ushort (bf16)
    unsigned short* B = A + (size_t)NN * HID;           // NN*HID ushort (bf16)
    float* pv   = (float*)(B + (size_t)NN * HID);       // 64

    const int* srcp = eidx;
    const int* dstp = eidx + NE;

    // ---- build CSR (by dst) + dinv; split W1/W2 + pocket ----
    hipMemsetAsync(cnt, 0, NN * sizeof(int), stream);
    hist_kernel<<<(NE + 255) / 256, 256, 0, stream>>>(dstp, cnt);
    scan_a<<<NTILES, 256, 0, stream>>>(cnt, rs, tsum, dinv);
    scan_b<<<1, 128, 0, stream>>>(tsum);
    scan_c<<<NTILES, 256, 0, stream>>>(rs, tsum, cnt);  // cnt becomes cursor
    bucket_kernel<<<(NE + 255) / 256, 256, 0, stream>>>(srcp, dstp, cnt, esrc);
    prep_kernel<<<65, 256, 0, stream>>>(W1, W2, w1hi, w1lo, w2hi, w2lo,
                                        pocket, pw1, pb1, pw2, pb2, pv);

    // ---- layer 0: aggregate x, then transform -> bf16 plane A ----
    xagg_kernel<<<(NN * 8 + 255) / 256, 256, 0, stream>>>(x, rs, esrc, dinv, xa);
    l0_transform<<<2048, 256, 0, stream>>>(xa, W0, b0,
                                           bn_gamma + 0 * HID, bn_beta + 0 * HID,
                                           bn_mean + 0 * HID, bn_var + 0 * HID, A);

    const int MM_BLOCKS = 1024;          // persistent, ~3 tiles/block
    const int GA_BLOCKS = (NN * 16 + 255) / 256;

    // ---- layer 1: A -> B(hl) -> A(h) ----
    mm_mfma<<<MM_BLOCKS, 256, 0, stream>>>(A, w1hi, w1lo, B);
    gather_bn<<<GA_BLOCKS, 256, 0, stream>>>(
        B, rs, esrc, dinv, b1,
        bn_gamma + 1 * HID, bn_beta + 1 * HID, bn_mean + 1 * HID, bn_var + 1 * HID, A);
    // ---- layer 2: A -> B(hl) -> A(h) ----
    mm_mfma<<<MM_BLOCKS, 256, 0, stream>>>(A, w2hi, w2lo, B);
    gather_bn<<<GA_BLOCKS, 256, 0, stream>>>(
        B, rs, esrc, dinv, b2,
        bn_gamma + 2 * HID, bn_beta + 2 * HID, bn_mean + 2 * HID, bn_var + 2 * HID, A);

    // fused pool + classifier (bf16 h)
    poolcls_kernel<<<NG, 1024, 0, stream>>>(A, batch, pv, cw1, cb1, cw2, cb2, out);
}